// Round 6
// baseline (458.116 us; speedup 1.0000x reference)
//
#include <hip/hip_runtime.h>
#include <cstdint>

typedef __attribute__((ext_vector_type(8))) short short8;
typedef __attribute__((ext_vector_type(8))) _Float16 half8;
typedef __attribute__((ext_vector_type(4))) float f32x4;

#define AS1 __attribute__((address_space(1)))
#define AS3 __attribute__((address_space(3)))

constexpr int NB   = 8;
constexpr int L    = 4096;
constexpr int CH   = 512;     // model dim == E_IN
constexpr int DD   = 64;
constexpr int NE   = 131072;
constexpr int M_ROWS = NB * L;  // 32768

__device__ __forceinline__ unsigned short f2bf(float f) {
    unsigned int x; __builtin_memcpy(&x, &f, 4);
    x += 0x7fffu + ((x >> 16) & 1u);
    return (unsigned short)(x >> 16);
}
// 2x f32 -> packed bf16 dword (lo=a, hi=b), single HW instr (verified gfx950)
__device__ __forceinline__ unsigned int cvt_pk_bf16(float a, float b) {
    unsigned int r;
    asm("v_cvt_pk_bf16_f32 %0, %1, %2" : "=v"(r) : "v"(a), "v"(b));
    return r;
}

// ---------------- f32 -> bf16 weight convert (2 MB total, tiny) ----------------
__global__ __launch_bounds__(256)
void cvtw_k(const float* __restrict__ s0, const float* __restrict__ s1,
            const float* __restrict__ s2, const float* __restrict__ s3,
            unsigned short* __restrict__ dst) {
    const float* s = (blockIdx.y == 0) ? s0 : (blockIdx.y == 1) ? s1
                   : (blockIdx.y == 2) ? s2 : s3;
    unsigned short* d = dst + (size_t)blockIdx.y * (CH * CH);
    const int i = blockIdx.x * 256 + threadIdx.x;
    const float4 a = ((const float4*)s)[i * 2];
    const float4 b = ((const float4*)s)[i * 2 + 1];
    unsigned short us[8];
    us[0] = f2bf(a.x); us[1] = f2bf(a.y); us[2] = f2bf(a.z); us[3] = f2bf(a.w);
    us[4] = f2bf(b.x); us[5] = f2bf(b.y); us[6] = f2bf(b.z); us[7] = f2bf(b.w);
    ((short8*)d)[i] = *(short8*)us;
}

// ---------------- projection GEMM (3-way): C[m][n] = A[m][k]*B[n][k] + bias[n]
// A f32 loaded DIRECT global->reg (dwordx4, in-reg reuse over fn; L2 reuse over
// col-blocks via XCD swizzle), converted with v_cvt_pk_bf16_f32 pre-barrier.
// LDS holds only B (16 KB) via global_load_lds width-16. Output f16.
// blockIdx.y selects {queries,keys,values}. 128x128 tile, BK=64, 4 waves 2x2.
__global__ __launch_bounds__(256, 2)
void gemm_proj(const float* __restrict__ Aq, const float* __restrict__ Ak,
               const float* __restrict__ Av,
               const float* __restrict__ bq, const float* __restrict__ bk,
               const float* __restrict__ bv,
               const unsigned short* __restrict__ wbf,
               _Float16* __restrict__ Cq, _Float16* __restrict__ Ck,
               _Float16* __restrict__ Cv)
{
    __shared__ unsigned short Bs[128 * 64];
    const int y = blockIdx.y;
    const float* A    = (y == 0) ? Aq : (y == 1) ? Ak : Av;
    const float* bias = (y == 0) ? bq : (y == 1) ? bk : bv;
    const unsigned short* B = wbf + (size_t)y * (CH * CH);
    _Float16* C = (y == 0) ? Cq : (y == 1) ? Ck : Cv;

    const int bid = blockIdx.x;                     // 1024 blocks per slice
    const int swz = (bid & 7) * 128 + (bid >> 3);   // bijective XCD swizzle
    const int row0 = (swz >> 2) * 128;
    const int col0 = (swz & 3) * 128;
    const int t = threadIdx.x, lane = t & 63, wid = t >> 6;
    const int wm = (wid >> 1) * 64, wn = (wid & 1) * 64;
    const int fr = lane & 15, fkb = (lane >> 4) * 8;
    const int srow = lane >> 3;          // B staging: row within 8-row chunk
    const int scol = (lane & 7) * 8;     // B staging: k-elem offset

    const float* arow[4];
#pragma unroll
    for (int f = 0; f < 4; f++)
        arow[f] = A + (size_t)(row0 + wm + f * 16 + fr) * CH;

    f32x4 acc[4][4] = {};

    for (int k0 = 0; k0 < CH; k0 += 64) {
#pragma unroll
        for (int q = 0; q < 4; q++) {
            const int r = wid * 32 + q * 8;
            __builtin_amdgcn_global_load_lds(
                (const AS1 unsigned int*)
                    (B + (size_t)(col0 + r + srow) * CH + k0 + scol),
                (AS3 unsigned int*)(Bs + r * 64), 16, 0, 0);
        }
        // A direct loads + convert (pre-barrier; barrier drains vmcnt anyway)
        short8 afr[2][4];
#pragma unroll
        for (int kk = 0; kk < 2; kk++)
#pragma unroll
            for (int f = 0; f < 4; f++) {
                const float* p = arow[f] + k0 + kk * 32 + fkb;
                const f32x4 x0 = *(const f32x4*)p;
                const f32x4 x1 = *(const f32x4*)(p + 4);
                unsigned int pk[4];
                pk[0] = cvt_pk_bf16(x0.x, x0.y);
                pk[1] = cvt_pk_bf16(x0.z, x0.w);
                pk[2] = cvt_pk_bf16(x1.x, x1.y);
                pk[3] = cvt_pk_bf16(x1.z, x1.w);
                afr[kk][f] = *(short8*)pk;
            }
        __syncthreads();
#pragma unroll
        for (int kk = 0; kk < 2; kk++) {
            short8 bfr[4];
#pragma unroll
            for (int f = 0; f < 4; f++)
                bfr[f] = *(const short8*)&Bs[(wn + f * 16 + fr) * 64 + kk * 32 + fkb];
#pragma unroll
            for (int fm = 0; fm < 4; fm++)
#pragma unroll
                for (int fn = 0; fn < 4; fn++)
                    acc[fm][fn] = __builtin_amdgcn_mfma_f32_16x16x32_bf16(
                        afr[kk][fm], bfr[fn], acc[fm][fn], 0, 0, 0);
        }
        __syncthreads();
    }

    const int rsub = (lane >> 4) * 4;
#pragma unroll
    for (int fn = 0; fn < 4; fn++) {
        const int gc = col0 + wn + fn * 16 + fr;
        const float bv2 = bias[gc];
#pragma unroll
        for (int fm = 0; fm < 4; fm++) {
            const int gr = row0 + wm + fm * 16 + rsub;
#pragma unroll
            for (int j = 0; j < 4; j++)
                C[(size_t)(gr + j) * CH + gc] = (_Float16)(acc[fm][fn][j] + bv2);
        }
    }
}

// ---------------- output GEMM: bf16 A (agg) x bf16 W -> f32 out
// Round-3 proven structure: both tiles via global_load_lds width-16.
__global__ __launch_bounds__(256)
void gemm_out(const unsigned short* __restrict__ A, const unsigned short* __restrict__ B,
              const float* __restrict__ bias, float* __restrict__ Cp)
{
    __shared__ unsigned short As[128 * 64];
    __shared__ unsigned short Bs[128 * 64];
    const int bid = blockIdx.x;                     // 1024 blocks
    const int swz = (bid & 7) * 128 + (bid >> 3);   // bijective XCD swizzle
    const int row0 = (swz >> 2) * 128;
    const int col0 = (swz & 3) * 128;
    const int t = threadIdx.x, lane = t & 63, wid = t >> 6;
    const int wm = (wid >> 1) * 64, wn = (wid & 1) * 64;
    const int fr = lane & 15, fkb = (lane >> 4) * 8;
    const int srow = lane >> 3;
    const int scol = (lane & 7) * 8;

    f32x4 acc[4][4] = {};

    for (int k0 = 0; k0 < CH; k0 += 64) {
#pragma unroll
        for (int q = 0; q < 4; q++) {
            const int r = wid * 32 + q * 8;
            __builtin_amdgcn_global_load_lds(
                (const AS1 unsigned int*)
                    (A + (size_t)(row0 + r + srow) * CH + k0 + scol),
                (AS3 unsigned int*)(As + r * 64), 16, 0, 0);
        }
#pragma unroll
        for (int q = 0; q < 4; q++) {
            const int r = wid * 32 + q * 8;
            __builtin_amdgcn_global_load_lds(
                (const AS1 unsigned int*)
                    (B + (size_t)(col0 + r + srow) * CH + k0 + scol),
                (AS3 unsigned int*)(Bs + r * 64), 16, 0, 0);
        }
        __syncthreads();
#pragma unroll
        for (int kk = 0; kk < 2; kk++) {
            short8 afr[4], bfr[4];
#pragma unroll
            for (int f = 0; f < 4; f++)
                afr[f] = *(const short8*)&As[(wm + f * 16 + fr) * 64 + kk * 32 + fkb];
#pragma unroll
            for (int f = 0; f < 4; f++)
                bfr[f] = *(const short8*)&Bs[(wn + f * 16 + fr) * 64 + kk * 32 + fkb];
#pragma unroll
            for (int fm = 0; fm < 4; fm++)
#pragma unroll
                for (int fn = 0; fn < 4; fn++)
                    acc[fm][fn] = __builtin_amdgcn_mfma_f32_16x16x32_bf16(
                        afr[fm], bfr[fn], acc[fm][fn], 0, 0, 0);
        }
        __syncthreads();
    }

    const int rsub = (lane >> 4) * 4;
#pragma unroll
    for (int fn = 0; fn < 4; fn++) {
        const int gc = col0 + wn + fn * 16 + fr;
        const float bv = bias[gc];
#pragma unroll
        for (int fm = 0; fm < 4; fm++) {
            const int gr = row0 + wm + fm * 16 + rsub;
#pragma unroll
            for (int j = 0; j < 4; j++)
                Cp[(size_t)(gr + j) * CH + gc] = acc[fm][fn][j] + bv;
        }
    }
}

// ---------------- CSR build ----------------
__global__ void zero_k(int* cnt, int* fill) {
    int i = blockIdx.x * blockDim.x + threadIdx.x;
    if (i < L) { cnt[i] = 0; fill[i] = 0; }
}
__global__ void count_k(const int* __restrict__ adj, int* __restrict__ cnt) {
    int e = blockIdx.x * blockDim.x + threadIdx.x;
    if (e < NE) atomicAdd(&cnt[adj[e]], 1);
}
__global__ void scan_k(const int* __restrict__ cnt, int* __restrict__ rowptr) {
    const int lane = threadIdx.x;      // 64 threads, 1 wave
    const int base = lane * 64;
    int s = 0;
    for (int t2 = 0; t2 < 64; t2++) s += cnt[base + t2];
    int incl = s;
    for (int off = 1; off < 64; off <<= 1) {
        int v = __shfl_up(incl, off);
        if (lane >= off) incl += v;
    }
    int run = incl - s;   // exclusive prefix
    for (int t2 = 0; t2 < 64; t2++) { rowptr[base + t2] = run; run += cnt[base + t2]; }
    if (lane == 63) rowptr[L] = run;
}
__global__ void scatter_k(const int* __restrict__ adj, const int* __restrict__ rowptr,
                          int* __restrict__ fill, int* __restrict__ ecol) {
    int e = blockIdx.x * blockDim.x + threadIdx.x;
    if (e < NE) {
        int rr = adj[e];
        int pos = rowptr[rr] + atomicAdd(&fill[rr], 1);
        ecol[pos] = adj[NE + e];
    }
}

// ---------------- fused edge-softmax + SPMM ----------------
// Round-3 proven structure; q/k/v now f16 so the dot and accumulate use
// v_fma_mix_f32 (fpext(f16) folded into FMA) instead of unpack+fma pairs.
// block = (i, n, hg): 256 threads = 4 waves, wave w = head hg*4+w.
// XCD pinning: n = bid & 7 -> per-XCD live K/V slice = 4 MB = one L2.
// Wave: 8 groups x 8 lanes; one edge/group/iter, lane g holds dims g*8..+7.
// No-max softmax (scores ~N(0,1); exp2-domain, scale folded into Q).
__global__ __launch_bounds__(256)
void attn_k(const _Float16* __restrict__ qb, const _Float16* __restrict__ kb,
            const _Float16* __restrict__ vb, const int* __restrict__ rowptr,
            const int* __restrict__ ecol, unsigned short* __restrict__ agg)
{
    __shared__ float part[4 * 8 * 65];   // [wave][grp][65] (stride 65: conflict-free)
    const int bid = blockIdx.x;
    const int n   = bid & 7;
    const int rem = bid >> 3;
    const int hg  = rem >> 12;          // 0 or 1
    const int i   = rem & 4095;
    const int lane = threadIdx.x & 63;
    const int w    = threadIdx.x >> 6;  // wave 0..3
    const int h    = hg * 4 + w;
    const int g    = lane & 7;          // dim-chunk within edge
    const int grp  = lane >> 3;         // edge slot 0..7
    const size_t rowbase = ((size_t)(n * L + i)) * CH + h * DD;

    // Q fragment, pre-scaled by 1/sqrt(64) * log2(e)
    constexpr float SCALE = 0.125f * 1.44269504088896f;
    float qf[8];
    {
        const half8 qu = *(const half8*)(qb + rowbase + g * 8);
#pragma unroll
        for (int e = 0; e < 8; e++) qf[e] = (float)qu[e] * SCALE;
    }
    const int start = rowptr[i], end = rowptr[i + 1];
    const char* kb_nh = (const char*)(kb + (size_t)n * L * CH + h * DD);
    const char* vb_nh = (const char*)(vb + (size_t)n * L * CH + h * DD);

    float o[8] = {};
    float lsum = 0.f;

    const int nIter = (end - start + 7) >> 3;
    int idx = start + grp;
    int j = (nIter > 0) ? ecol[min(idx, end - 1)] : 0;
    for (int it = 0; it < nIter; ++it) {
        const bool valid = idx < end;
        const int off = (j << 10) + (g << 4);
        const half8 ku = *(const half8*)(kb_nh + off);
        const half8 vu = *(const half8*)(vb_nh + off);
        // prefetch next iteration's column index (hides ecol->K dependency)
        const int idxn = idx + 8;
        const int jn = ecol[min(idxn, end - 1)];
        float s0 = 0.f, s1 = 0.f;
#pragma unroll
        for (int e = 0; e < 4; e++) {
            s0 = fmaf((float)ku[2 * e],     qf[2 * e],     s0);  // v_fma_mix_f32
            s1 = fmaf((float)ku[2 * e + 1], qf[2 * e + 1], s1);
        }
        float s = s0 + s1;
        s += __shfl_xor(s, 1);
        s += __shfl_xor(s, 2);
        s += __shfl_xor(s, 4);
        float pe = exp2f(s);
        pe = valid ? pe : 0.f;
#pragma unroll
        for (int e = 0; e < 8; e++)
            o[e] = fmaf((float)vu[e], pe, o[e]);                 // v_fma_mix_f32
        lsum += pe;
        idx = idxn;
        j = jn;
    }

    // total lsum across the 8 groups (lsum is uniform within a group)
    lsum += __shfl_xor(lsum, 8);
    lsum += __shfl_xor(lsum, 16);
    lsum += __shfl_xor(lsum, 32);

    // merge o across groups via per-wave LDS transpose
    float* p = part + w * (8 * 65);
    float* pw = p + grp * 65 + g * 8;
    *(f32x4*)(pw)     = *(f32x4*)&o[0];
    *(f32x4*)(pw + 4) = *(f32x4*)&o[4];
    __builtin_amdgcn_s_waitcnt(0);  // lgkm drain (same-wave LDS RAW)
    float osum = 0.f;
#pragma unroll
    for (int gg = 0; gg < 8; gg++)
        osum += p[gg * 65 + lane];

    const float inv = (end > start) ? 1.f / lsum : 0.f;
    agg[rowbase + lane] = f2bf(osum * inv);
}

extern "C" void kernel_launch(void* const* d_in, const int* in_sizes, int n_in,
                              void* d_out, int out_size, void* d_ws, size_t ws_size,
                              hipStream_t stream)
{
    (void)in_sizes; (void)n_in; (void)out_size; (void)ws_size;
    const float* queries = (const float*)d_in[0];
    const float* keys    = (const float*)d_in[1];
    const float* values  = (const float*)d_in[2];
    const int*   adj     = (const int*)d_in[3];
    const float* Wq  = (const float*)d_in[4];
    const float* bq  = (const float*)d_in[5];
    const float* Wk  = (const float*)d_in[6];
    const float* bk  = (const float*)d_in[7];
    const float* Wv  = (const float*)d_in[8];
    const float* bv  = (const float*)d_in[9];
    const float* Wfc = (const float*)d_in[10];
    const float* bfc = (const float*)d_in[11];

    // q/k f16 projections live inside d_out (dead before final GEMM writes it)
    _Float16* qb = (_Float16*)d_out;                   // 33.5 MB
    _Float16* kb = qb + (size_t)M_ROWS * CH;           // 33.5 MB
    uint8_t* w = (uint8_t*)d_ws;
    _Float16* vb = (_Float16*)(w);                                // 33.5 MB
    unsigned short* agg = (unsigned short*)(w + 33554432);        // 33.5 MB (bf16)
    unsigned short* wbf = (unsigned short*)(w + 67108864);        // 2 MB (4 weights)
    int* cnt    = (int*)(w + 69206016);
    int* fill   = (int*)(w + 69206016 + 16384);
    int* rowptr = (int*)(w + 69206016 + 32768);
    int* ecol   = (int*)(w + 69206016 + 65536);                   // 512 KB

    constexpr int WELEM = CH * CH;  // 262144

    cvtw_k<<<dim3(WELEM / (256 * 8), 4), 256, 0, stream>>>(Wq, Wk, Wv, Wfc, wbf);

    zero_k<<<(L + 255) / 256, 256, 0, stream>>>(cnt, fill);
    count_k<<<(NE + 255) / 256, 256, 0, stream>>>(adj, cnt);
    scan_k<<<1, 64, 0, stream>>>(cnt, rowptr);
    scatter_k<<<(NE + 255) / 256, 256, 0, stream>>>(adj, rowptr, fill, ecol);

    gemm_proj<<<dim3(1024, 3), 256, 0, stream>>>(queries, keys, values,
                                                 bq, bk, bv, wbf, qb, kb, vb);

    attn_k<<<dim3(2 * NB * L), 256, 0, stream>>>(qb, kb, vb, rowptr, ecol, agg);
    // grid = 2(hg) * 8(n) * 4096(i) = 65536 blocks

    gemm_out<<<dim3(1024), 256, 0, stream>>>(agg, wbf + 3 * WELEM, bfc, (float*)d_out);
}

// Round 8
// 385.881 us; speedup vs baseline: 1.1872x; 1.1872x over previous
//
#include <hip/hip_runtime.h>
#include <cstdint>

typedef __attribute__((ext_vector_type(8))) short short8;
typedef __attribute__((ext_vector_type(8))) _Float16 half8;
typedef __attribute__((ext_vector_type(2))) __fp16 fp16x2;
typedef __attribute__((ext_vector_type(4))) float f32x4;

#define AS1 __attribute__((address_space(1)))
#define AS3 __attribute__((address_space(3)))

constexpr int NB   = 8;
constexpr int L    = 4096;
constexpr int CH   = 512;     // model dim == E_IN
constexpr int DD   = 64;
constexpr int NE   = 131072;
constexpr int M_ROWS = NB * L;  // 32768

// ---------------- f32 -> f16 convert kernels (packed cvt_pkrtz) ----------------
__global__ __launch_bounds__(256)
void cvt8_k(const float* __restrict__ src, _Float16* __restrict__ dst) {
    const int i = blockIdx.x * 256 + threadIdx.x;   // one per 8 elems
    const f32x4 a = ((const f32x4*)src)[i * 2];
    const f32x4 b = ((const f32x4*)src)[i * 2 + 1];
    fp16x2 h[4];
    h[0] = __builtin_amdgcn_cvt_pkrtz(a.x, a.y);
    h[1] = __builtin_amdgcn_cvt_pkrtz(a.z, a.w);
    h[2] = __builtin_amdgcn_cvt_pkrtz(b.x, b.y);
    h[3] = __builtin_amdgcn_cvt_pkrtz(b.z, b.w);
    half8 out;
    __builtin_memcpy(&out, h, 16);
    ((half8*)dst)[i] = out;
}

__global__ __launch_bounds__(256)
void cvtw_k(const float* __restrict__ s0, const float* __restrict__ s1,
            const float* __restrict__ s2, const float* __restrict__ s3,
            _Float16* __restrict__ dst) {
    const float* s = (blockIdx.y == 0) ? s0 : (blockIdx.y == 1) ? s1
                   : (blockIdx.y == 2) ? s2 : s3;
    _Float16* d = dst + (size_t)blockIdx.y * (CH * CH);
    const int i = blockIdx.x * 256 + threadIdx.x;
    const f32x4 a = ((const f32x4*)s)[i * 2];
    const f32x4 b = ((const f32x4*)s)[i * 2 + 1];
    fp16x2 h[4];
    h[0] = __builtin_amdgcn_cvt_pkrtz(a.x, a.y);
    h[1] = __builtin_amdgcn_cvt_pkrtz(a.z, a.w);
    h[2] = __builtin_amdgcn_cvt_pkrtz(b.x, b.y);
    h[3] = __builtin_amdgcn_cvt_pkrtz(b.z, b.w);
    half8 out;
    __builtin_memcpy(&out, h, 16);
    ((half8*)d)[i] = out;
}

// ---------------- f16 B^T GEMM: C[m][n] = sum_k A[m][k]*B[n][k] + bias[n]
// M=32768, N=512, K=512. 128x128 tile, BK=64, 256 thr (4 waves 2x2),
// global_load_lds width-16 staging for BOTH tiles (round-3 proven structure),
// XCD-swizzled block id. mfma_f32_16x16x32_f16 (same rate as bf16).
template <bool OUT_F32>
__global__ __launch_bounds__(256)
void gemm_f16(const _Float16* __restrict__ A, const _Float16* __restrict__ B,
              const float* __restrict__ bias, void* __restrict__ Cp)
{
    __shared__ _Float16 As[128 * 64];
    __shared__ _Float16 Bs[128 * 64];
    const int bid = blockIdx.x;                     // 1024 blocks
    const int swz = (bid & 7) * 128 + (bid >> 3);   // bijective XCD swizzle
    const int row0 = (swz >> 2) * 128;
    const int col0 = (swz & 3) * 128;
    const int t = threadIdx.x, lane = t & 63, wid = t >> 6;
    const int wm = (wid >> 1) * 64, wn = (wid & 1) * 64;
    const int fr = lane & 15, fkb = (lane >> 4) * 8;
    const int srow = lane >> 3;          // staging row within 8-row chunk
    const int scol = (lane & 7) * 8;     // staging k-elem offset

    f32x4 acc[4][4] = {};

    for (int k0 = 0; k0 < CH; k0 += 64) {
#pragma unroll
        for (int q = 0; q < 4; q++) {
            const int r = wid * 32 + q * 8;
            __builtin_amdgcn_global_load_lds(
                (const AS1 unsigned int*)
                    (A + (size_t)(row0 + r + srow) * CH + k0 + scol),
                (AS3 unsigned int*)(As + r * 64), 16, 0, 0);
        }
#pragma unroll
        for (int q = 0; q < 4; q++) {
            const int r = wid * 32 + q * 8;
            __builtin_amdgcn_global_load_lds(
                (const AS1 unsigned int*)
                    (B + (size_t)(col0 + r + srow) * CH + k0 + scol),
                (AS3 unsigned int*)(Bs + r * 64), 16, 0, 0);
        }
        __syncthreads();
#pragma unroll
        for (int kk = 0; kk < 2; kk++) {
            half8 afr[4], bfr[4];
#pragma unroll
            for (int f = 0; f < 4; f++)
                afr[f] = *(const half8*)&As[(wm + f * 16 + fr) * 64 + kk * 32 + fkb];
#pragma unroll
            for (int f = 0; f < 4; f++)
                bfr[f] = *(const half8*)&Bs[(wn + f * 16 + fr) * 64 + kk * 32 + fkb];
#pragma unroll
            for (int fm = 0; fm < 4; fm++)
#pragma unroll
                for (int fn = 0; fn < 4; fn++)
                    acc[fm][fn] = __builtin_amdgcn_mfma_f32_16x16x32_f16(
                        afr[fm], bfr[fn], acc[fm][fn], 0, 0, 0);
        }
        __syncthreads();
    }

    const int rsub = (lane >> 4) * 4;
#pragma unroll
    for (int fn = 0; fn < 4; fn++) {
        const int gc = col0 + wn + fn * 16 + fr;
        const float bv = bias[gc];
#pragma unroll
        for (int fm = 0; fm < 4; fm++) {
            const int gr = row0 + wm + fm * 16 + rsub;
#pragma unroll
            for (int j = 0; j < 4; j++) {
                const float v = acc[fm][fn][j] + bv;
                if constexpr (OUT_F32)
                    ((float*)Cp)[(size_t)(gr + j) * CH + gc] = v;
                else
                    ((_Float16*)Cp)[(size_t)(gr + j) * CH + gc] = (_Float16)v;
            }
        }
    }
}

// ---------------- CSR build ----------------
__global__ void zero_k(int* cnt, int* fill) {
    int i = blockIdx.x * blockDim.x + threadIdx.x;
    if (i < L) { cnt[i] = 0; fill[i] = 0; }
}
__global__ void count_k(const int* __restrict__ adj, int* __restrict__ cnt) {
    int e = blockIdx.x * blockDim.x + threadIdx.x;
    if (e < NE) atomicAdd(&cnt[adj[e]], 1);
}
__global__ void scan_k(const int* __restrict__ cnt, int* __restrict__ rowptr) {
    const int lane = threadIdx.x;      // 64 threads, 1 wave
    const int base = lane * 64;
    int s = 0;
    for (int t2 = 0; t2 < 64; t2++) s += cnt[base + t2];
    int incl = s;
    for (int off = 1; off < 64; off <<= 1) {
        int v = __shfl_up(incl, off);
        if (lane >= off) incl += v;
    }
    int run = incl - s;   // exclusive prefix
    for (int t2 = 0; t2 < 64; t2++) { rowptr[base + t2] = run; run += cnt[base + t2]; }
    if (lane == 63) rowptr[L] = run;
}
__global__ void scatter_k(const int* __restrict__ adj, const int* __restrict__ rowptr,
                          int* __restrict__ fill, int* __restrict__ ecol) {
    int e = blockIdx.x * blockDim.x + threadIdx.x;
    if (e < NE) {
        int rr = adj[e];
        int pos = rowptr[rr] + atomicAdd(&fill[rr], 1);
        ecol[pos] = adj[NE + e];
    }
}

// ---------------- fused edge-softmax + SPMM ----------------
// Round-3 proven structure; q/k/v f16 so dot/accumulate use v_fma_mix_f32
// (fpext(f16) folded into FMA -> no unpack instrs).
// block = (i, n, hg): 256 threads = 4 waves, wave w = head hg*4+w.
// XCD pinning: n = bid & 7 -> per-XCD live K/V slice = 4 MB = one L2.
// Wave: 8 groups x 8 lanes; one edge/group/iter, lane g holds dims g*8..+7.
// No-max softmax (scores ~N(0,1); exp2-domain, scale folded into Q).
__global__ __launch_bounds__(256)
void attn_k(const _Float16* __restrict__ qb, const _Float16* __restrict__ kb,
            const _Float16* __restrict__ vb, const int* __restrict__ rowptr,
            const int* __restrict__ ecol, _Float16* __restrict__ agg)
{
    __shared__ float part[4 * 8 * 65];   // [wave][grp][65] (stride 65: conflict-free)
    const int bid = blockIdx.x;
    const int n   = bid & 7;
    const int rem = bid >> 3;
    const int hg  = rem >> 12;          // 0 or 1
    const int i   = rem & 4095;
    const int lane = threadIdx.x & 63;
    const int w    = threadIdx.x >> 6;  // wave 0..3
    const int h    = hg * 4 + w;
    const int g    = lane & 7;          // dim-chunk within edge
    const int grp  = lane >> 3;         // edge slot 0..7
    const size_t rowbase = ((size_t)(n * L + i)) * CH + h * DD;

    // Q fragment, pre-scaled by 1/sqrt(64) * log2(e)
    constexpr float SCALE = 0.125f * 1.44269504088896f;
    float qf[8];
    {
        const half8 qu = *(const half8*)(qb + rowbase + g * 8);
#pragma unroll
        for (int e = 0; e < 8; e++) qf[e] = (float)qu[e] * SCALE;
    }
    const int start = rowptr[i], end = rowptr[i + 1];
    const char* kb_nh = (const char*)(kb + (size_t)n * L * CH + h * DD);
    const char* vb_nh = (const char*)(vb + (size_t)n * L * CH + h * DD);

    float o[8] = {};
    float lsum = 0.f;

    const int nIter = (end - start + 7) >> 3;
    int idx = start + grp;
    int j = (nIter > 0) ? ecol[min(idx, end - 1)] : 0;
    for (int it = 0; it < nIter; ++it) {
        const bool valid = idx < end;
        const int off = (j << 10) + (g << 4);
        const half8 ku = *(const half8*)(kb_nh + off);
        const half8 vu = *(const half8*)(vb_nh + off);
        // prefetch next iteration's column index (hides ecol->K dependency)
        const int idxn = idx + 8;
        const int jn = ecol[min(idxn, end - 1)];
        float s0 = 0.f, s1 = 0.f;
#pragma unroll
        for (int e = 0; e < 4; e++) {
            s0 = fmaf((float)ku[2 * e],     qf[2 * e],     s0);  // v_fma_mix_f32
            s1 = fmaf((float)ku[2 * e + 1], qf[2 * e + 1], s1);
        }
        float s = s0 + s1;
        s += __shfl_xor(s, 1);
        s += __shfl_xor(s, 2);
        s += __shfl_xor(s, 4);
        float pe = exp2f(s);
        pe = valid ? pe : 0.f;
#pragma unroll
        for (int e = 0; e < 8; e++)
            o[e] = fmaf((float)vu[e], pe, o[e]);                 // v_fma_mix_f32
        lsum += pe;
        idx = idxn;
        j = jn;
    }

    // total lsum across the 8 groups (lsum is uniform within a group)
    lsum += __shfl_xor(lsum, 8);
    lsum += __shfl_xor(lsum, 16);
    lsum += __shfl_xor(lsum, 32);

    // merge o across groups via per-wave LDS transpose
    float* p = part + w * (8 * 65);
    float* pw = p + grp * 65 + g * 8;
    *(f32x4*)(pw)     = *(f32x4*)&o[0];
    *(f32x4*)(pw + 4) = *(f32x4*)&o[4];
    __builtin_amdgcn_s_waitcnt(0);  // lgkm drain (same-wave LDS RAW)
    float osum = 0.f;
#pragma unroll
    for (int gg = 0; gg < 8; gg++)
        osum += p[gg * 65 + lane];

    const float inv = (end > start) ? 1.f / lsum : 0.f;
    agg[rowbase + lane] = (_Float16)(osum * inv);
}

extern "C" void kernel_launch(void* const* d_in, const int* in_sizes, int n_in,
                              void* d_out, int out_size, void* d_ws, size_t ws_size,
                              hipStream_t stream)
{
    (void)in_sizes; (void)n_in; (void)out_size; (void)ws_size;
    const float* queries = (const float*)d_in[0];
    const float* keys    = (const float*)d_in[1];
    const float* values  = (const float*)d_in[2];
    const int*   adj     = (const int*)d_in[3];
    const float* Wq  = (const float*)d_in[4];
    const float* bq  = (const float*)d_in[5];
    const float* Wk  = (const float*)d_in[6];
    const float* bk  = (const float*)d_in[7];
    const float* Wv  = (const float*)d_in[8];
    const float* bv  = (const float*)d_in[9];
    const float* Wfc = (const float*)d_in[10];
    const float* bfc = (const float*)d_in[11];

    // q/k f16 projections live inside d_out (dead before final GEMM writes it)
    _Float16* qb = (_Float16*)d_out;                   // 33.5 MB
    _Float16* kb = qb + (size_t)M_ROWS * CH;           // 33.5 MB
    uint8_t* w = (uint8_t*)d_ws;
    _Float16* vb  = (_Float16*)(w);                               // 33.5 MB
    _Float16* agg = (_Float16*)(w + 33554432);                    // 33.5 MB (also cvt staging)
    _Float16* wf  = (_Float16*)(w + 67108864);                    // 2 MB (4 weights)
    int* cnt    = (int*)(w + 69206016);
    int* fill   = (int*)(w + 69206016 + 16384);
    int* rowptr = (int*)(w + 69206016 + 32768);
    int* ecol   = (int*)(w + 69206016 + 65536);                   // 512 KB

    _Float16* stg = agg;   // cvt staging aliases agg (agg written later by attn)
    constexpr int WELEM = CH * CH;  // 262144

    cvtw_k<<<dim3(WELEM / (256 * 8), 4), 256, 0, stream>>>(Wq, Wk, Wv, Wfc, wf);

    zero_k<<<(L + 255) / 256, 256, 0, stream>>>(cnt, fill);
    count_k<<<(NE + 255) / 256, 256, 0, stream>>>(adj, cnt);
    scan_k<<<1, 64, 0, stream>>>(cnt, rowptr);
    scatter_k<<<(NE + 255) / 256, 256, 0, stream>>>(adj, rowptr, fill, ecol);

    dim3 gg(1024);  // (M/128)*(N/128) = 256*4
    cvt8_k<<<M_ROWS * CH / (256 * 8), 256, 0, stream>>>(queries, stg);
    gemm_f16<false><<<gg, 256, 0, stream>>>(stg, wf + 0 * WELEM, bq, qb);
    cvt8_k<<<M_ROWS * CH / (256 * 8), 256, 0, stream>>>(keys, stg);
    gemm_f16<false><<<gg, 256, 0, stream>>>(stg, wf + 1 * WELEM, bk, kb);
    cvt8_k<<<M_ROWS * CH / (256 * 8), 256, 0, stream>>>(values, stg);
    gemm_f16<false><<<gg, 256, 0, stream>>>(stg, wf + 2 * WELEM, bv, vb);

    attn_k<<<dim3(2 * NB * L), 256, 0, stream>>>(qb, kb, vb, rowptr, ecol, agg);
    // grid = 2(hg) * 8(n) * 4096(i) = 65536 blocks

    gemm_f16<true><<<gg, 256, 0, stream>>>(agg, wf + 3 * WELEM, bfc, (float*)d_out);
}

// Round 9
// 371.711 us; speedup vs baseline: 1.2325x; 1.0381x over previous
//
#include <hip/hip_runtime.h>
#include <cstdint>

typedef __attribute__((ext_vector_type(8))) short short8;
typedef __attribute__((ext_vector_type(8))) _Float16 half8;
typedef __attribute__((ext_vector_type(2))) __fp16 fp16x2;
typedef __attribute__((ext_vector_type(4))) float f32x4;

#define AS1 __attribute__((address_space(1)))
#define AS3 __attribute__((address_space(3)))

constexpr int NB   = 8;
constexpr int L    = 4096;
constexpr int CH   = 512;     // model dim == E_IN
constexpr int DD   = 64;
constexpr int NE   = 131072;
constexpr int M_ROWS = NB * L;  // 32768

// 8-lane sum reduce in VALU pipe only (no DS ops): quad xor1, xor2, then
// half-row mirror (lane i <-> 7-i within each 8) completes the 8-lane sum.
template <int CTRL>
__device__ __forceinline__ float dppadd(float s) {
    union { float f; int i; } u, r;
    u.f = s;
    r.i = __builtin_amdgcn_update_dpp(0, u.i, CTRL, 0xF, 0xF, true);
    return s + r.f;
}

// ---------------- f32 -> f16 convert kernels (packed cvt_pkrtz) ----------------
__global__ __launch_bounds__(256)
void cvt8_k(const float* __restrict__ src, _Float16* __restrict__ dst) {
    const int i = blockIdx.x * 256 + threadIdx.x;   // one per 8 elems
    const f32x4 a = ((const f32x4*)src)[i * 2];
    const f32x4 b = ((const f32x4*)src)[i * 2 + 1];
    fp16x2 h[4];
    h[0] = __builtin_amdgcn_cvt_pkrtz(a.x, a.y);
    h[1] = __builtin_amdgcn_cvt_pkrtz(a.z, a.w);
    h[2] = __builtin_amdgcn_cvt_pkrtz(b.x, b.y);
    h[3] = __builtin_amdgcn_cvt_pkrtz(b.z, b.w);
    half8 out;
    __builtin_memcpy(&out, h, 16);
    ((half8*)dst)[i] = out;
}

__global__ __launch_bounds__(256)
void cvtw_k(const float* __restrict__ s0, const float* __restrict__ s1,
            const float* __restrict__ s2, const float* __restrict__ s3,
            _Float16* __restrict__ dst) {
    const float* s = (blockIdx.y == 0) ? s0 : (blockIdx.y == 1) ? s1
                   : (blockIdx.y == 2) ? s2 : s3;
    _Float16* d = dst + (size_t)blockIdx.y * (CH * CH);
    const int i = blockIdx.x * 256 + threadIdx.x;
    const f32x4 a = ((const f32x4*)s)[i * 2];
    const f32x4 b = ((const f32x4*)s)[i * 2 + 1];
    fp16x2 h[4];
    h[0] = __builtin_amdgcn_cvt_pkrtz(a.x, a.y);
    h[1] = __builtin_amdgcn_cvt_pkrtz(a.z, a.w);
    h[2] = __builtin_amdgcn_cvt_pkrtz(b.x, b.y);
    h[3] = __builtin_amdgcn_cvt_pkrtz(b.z, b.w);
    half8 out;
    __builtin_memcpy(&out, h, 16);
    ((half8*)d)[i] = out;
}

// ---------------- f16 B^T GEMM: C[m][n] = sum_k A[m][k]*B[n][k] + bias[n]
// M=32768, N=512, K=512. 128x128 tile, BK=64, 256 thr (4 waves 2x2),
// global_load_lds width-16 staging for BOTH tiles, XCD-swizzled block id.
template <bool OUT_F32>
__global__ __launch_bounds__(256)
void gemm_f16(const _Float16* __restrict__ A, const _Float16* __restrict__ B,
              const float* __restrict__ bias, void* __restrict__ Cp)
{
    __shared__ _Float16 As[128 * 64];
    __shared__ _Float16 Bs[128 * 64];
    const int bid = blockIdx.x;                     // 1024 blocks
    const int swz = (bid & 7) * 128 + (bid >> 3);   // bijective XCD swizzle
    const int row0 = (swz >> 2) * 128;
    const int col0 = (swz & 3) * 128;
    const int t = threadIdx.x, lane = t & 63, wid = t >> 6;
    const int wm = (wid >> 1) * 64, wn = (wid & 1) * 64;
    const int fr = lane & 15, fkb = (lane >> 4) * 8;
    const int srow = lane >> 3;          // staging row within 8-row chunk
    const int scol = (lane & 7) * 8;     // staging k-elem offset

    f32x4 acc[4][4] = {};

    for (int k0 = 0; k0 < CH; k0 += 64) {
#pragma unroll
        for (int q = 0; q < 4; q++) {
            const int r = wid * 32 + q * 8;
            __builtin_amdgcn_global_load_lds(
                (const AS1 unsigned int*)
                    (A + (size_t)(row0 + r + srow) * CH + k0 + scol),
                (AS3 unsigned int*)(As + r * 64), 16, 0, 0);
        }
#pragma unroll
        for (int q = 0; q < 4; q++) {
            const int r = wid * 32 + q * 8;
            __builtin_amdgcn_global_load_lds(
                (const AS1 unsigned int*)
                    (B + (size_t)(col0 + r + srow) * CH + k0 + scol),
                (AS3 unsigned int*)(Bs + r * 64), 16, 0, 0);
        }
        __syncthreads();
#pragma unroll
        for (int kk = 0; kk < 2; kk++) {
            half8 afr[4], bfr[4];
#pragma unroll
            for (int f = 0; f < 4; f++)
                afr[f] = *(const half8*)&As[(wm + f * 16 + fr) * 64 + kk * 32 + fkb];
#pragma unroll
            for (int f = 0; f < 4; f++)
                bfr[f] = *(const half8*)&Bs[(wn + f * 16 + fr) * 64 + kk * 32 + fkb];
#pragma unroll
            for (int fm = 0; fm < 4; fm++)
#pragma unroll
                for (int fn = 0; fn < 4; fn++)
                    acc[fm][fn] = __builtin_amdgcn_mfma_f32_16x16x32_f16(
                        afr[fm], bfr[fn], acc[fm][fn], 0, 0, 0);
        }
        __syncthreads();
    }

    const int rsub = (lane >> 4) * 4;
#pragma unroll
    for (int fn = 0; fn < 4; fn++) {
        const int gc = col0 + wn + fn * 16 + fr;
        const float bv = bias[gc];
#pragma unroll
        for (int fm = 0; fm < 4; fm++) {
            const int gr = row0 + wm + fm * 16 + rsub;
#pragma unroll
            for (int j = 0; j < 4; j++) {
                const float v = acc[fm][fn][j] + bv;
                if constexpr (OUT_F32)
                    ((float*)Cp)[(size_t)(gr + j) * CH + gc] = v;
                else
                    ((_Float16*)Cp)[(size_t)(gr + j) * CH + gc] = (_Float16)v;
            }
        }
    }
}

// ---------------- CSR build ----------------
__global__ void zero_k(int* cnt, int* fill) {
    int i = blockIdx.x * blockDim.x + threadIdx.x;
    if (i < L) { cnt[i] = 0; fill[i] = 0; }
}
__global__ void count_k(const int* __restrict__ adj, int* __restrict__ cnt) {
    int e = blockIdx.x * blockDim.x + threadIdx.x;
    if (e < NE) atomicAdd(&cnt[adj[e]], 1);
}
__global__ void scan_k(const int* __restrict__ cnt, int* __restrict__ rowptr) {
    const int lane = threadIdx.x;      // 64 threads, 1 wave
    const int base = lane * 64;
    int s = 0;
    for (int t2 = 0; t2 < 64; t2++) s += cnt[base + t2];
    int incl = s;
    for (int off = 1; off < 64; off <<= 1) {
        int v = __shfl_up(incl, off);
        if (lane >= off) incl += v;
    }
    int run = incl - s;   // exclusive prefix
    for (int t2 = 0; t2 < 64; t2++) { rowptr[base + t2] = run; run += cnt[base + t2]; }
    if (lane == 63) rowptr[L] = run;
}
__global__ void scatter_k(const int* __restrict__ adj, const int* __restrict__ rowptr,
                          int* __restrict__ fill, int* __restrict__ ecol) {
    int e = blockIdx.x * blockDim.x + threadIdx.x;
    if (e < NE) {
        int rr = adj[e];
        int pos = rowptr[rr] + atomicAdd(&fill[rr], 1);
        ecol[pos] = adj[NE + e];
    }
}

// ---------------- fused edge-softmax + SPMM ----------------
// Round-3 structure + f16 fma_mix diet + 1-deep software pipeline:
// iteration it issues it+1's K/V loads and it+2's ecol index BEFORE computing,
// so the ecol->K L2 chain (~400cy) overlaps compute. 8-lane dot reduce via
// DPP adds (VALU pipe, no DS round-trips).
// block = (i, n, hg): 256 threads = 4 waves, wave w = head hg*4+w.
// XCD pinning: n = bid & 7 -> per-XCD live K/V slice = 4 MB = one L2.
__global__ __launch_bounds__(256)
void attn_k(const _Float16* __restrict__ qb, const _Float16* __restrict__ kb,
            const _Float16* __restrict__ vb, const int* __restrict__ rowptr,
            const int* __restrict__ ecol, _Float16* __restrict__ agg)
{
    __shared__ float part[4 * 8 * 65];   // [wave][grp][65] (stride 65: conflict-free)
    const int bid = blockIdx.x;
    const int n   = bid & 7;
    const int rem = bid >> 3;
    const int hg  = rem >> 12;          // 0 or 1
    const int i   = rem & 4095;
    const int lane = threadIdx.x & 63;
    const int w    = threadIdx.x >> 6;  // wave 0..3
    const int h    = hg * 4 + w;
    const int g    = lane & 7;          // dim-chunk within edge
    const int grp  = lane >> 3;         // edge slot 0..7
    const size_t rowbase = ((size_t)(n * L + i)) * CH + h * DD;

    // Q fragment, pre-scaled by 1/sqrt(64) * log2(e)
    constexpr float SCALE = 0.125f * 1.44269504088896f;
    float qf[8];
    {
        const half8 qu = *(const half8*)(qb + rowbase + g * 8);
#pragma unroll
        for (int e = 0; e < 8; e++) qf[e] = (float)qu[e] * SCALE;
    }
    const int start = rowptr[i], end = rowptr[i + 1];
    const char* kb_g = (const char*)(kb + (size_t)n * L * CH + h * DD) + (g << 4);
    const char* vb_g = (const char*)(vb + (size_t)n * L * CH + h * DD) + (g << 4);

    float o[8] = {};
    float lsum = 0.f;

    const int nIter = (end - start + 7) >> 3;
    int idx = start + grp;
    const int last = end - 1;
    // pipeline prologue: current K/V + next column index
    int j0 = (nIter > 0) ? ecol[min(idx, last)] : 0;
    half8 ku = *(const half8*)(kb_g + (j0 << 10));
    half8 vu = *(const half8*)(vb_g + (j0 << 10));
    int j1 = (nIter > 0) ? ecol[min(idx + 8, last)] : 0;

    for (int it = 0; it < nIter; ++it) {
        // issue next iteration's K/V loads and it+2's index first
        const half8 kun = *(const half8*)(kb_g + (j1 << 10));
        const half8 vun = *(const half8*)(vb_g + (j1 << 10));
        const int j2 = ecol[min(idx + 16, last)];
        const bool valid = idx < end;
        // compute with current ku/vu (already in flight one full iteration)
        float s0 = 0.f, s1 = 0.f;
#pragma unroll
        for (int e = 0; e < 4; e++) {
            s0 = fmaf((float)ku[2 * e],     qf[2 * e],     s0);  // v_fma_mix_f32
            s1 = fmaf((float)ku[2 * e + 1], qf[2 * e + 1], s1);
        }
        float s = s0 + s1;
        s = dppadd<0xB1>(s);    // + lane^1 (quad_perm [1,0,3,2])
        s = dppadd<0x4E>(s);    // + lane^2 (quad_perm [2,3,0,1])
        s = dppadd<0x141>(s);   // + mirrored half-row (completes 8-lane sum)
        float pe = exp2f(s);
        pe = valid ? pe : 0.f;
#pragma unroll
        for (int e = 0; e < 8; e++)
            o[e] = fmaf((float)vu[e], pe, o[e]);                 // v_fma_mix_f32
        lsum += pe;
        // rotate pipeline
        ku = kun; vu = vun; j1 = j2; idx += 8;
    }

    // total lsum across the 8 groups (lsum is uniform within a group)
    lsum += __shfl_xor(lsum, 8);
    lsum += __shfl_xor(lsum, 16);
    lsum += __shfl_xor(lsum, 32);

    // merge o across groups via per-wave LDS transpose
    float* p = part + w * (8 * 65);
    float* pw = p + grp * 65 + g * 8;
    *(f32x4*)(pw)     = *(f32x4*)&o[0];
    *(f32x4*)(pw + 4) = *(f32x4*)&o[4];
    __builtin_amdgcn_s_waitcnt(0);  // lgkm drain (same-wave LDS RAW)
    float osum = 0.f;
#pragma unroll
    for (int gg = 0; gg < 8; gg++)
        osum += p[gg * 65 + lane];

    const float inv = (end > start) ? 1.f / lsum : 0.f;
    agg[rowbase + lane] = (_Float16)(osum * inv);
}

extern "C" void kernel_launch(void* const* d_in, const int* in_sizes, int n_in,
                              void* d_out, int out_size, void* d_ws, size_t ws_size,
                              hipStream_t stream)
{
    (void)in_sizes; (void)n_in; (void)out_size; (void)ws_size;
    const float* queries = (const float*)d_in[0];
    const float* keys    = (const float*)d_in[1];
    const float* values  = (const float*)d_in[2];
    const int*   adj     = (const int*)d_in[3];
    const float* Wq  = (const float*)d_in[4];
    const float* bq  = (const float*)d_in[5];
    const float* Wk  = (const float*)d_in[6];
    const float* bk  = (const float*)d_in[7];
    const float* Wv  = (const float*)d_in[8];
    const float* bv  = (const float*)d_in[9];
    const float* Wfc = (const float*)d_in[10];
    const float* bfc = (const float*)d_in[11];

    // q/k f16 projections live inside d_out (dead before final GEMM writes it)
    _Float16* qb = (_Float16*)d_out;                   // 33.5 MB
    _Float16* kb = qb + (size_t)M_ROWS * CH;           // 33.5 MB
    uint8_t* w = (uint8_t*)d_ws;
    _Float16* vb  = (_Float16*)(w);                               // 33.5 MB
    _Float16* agg = (_Float16*)(w + 33554432);                    // 33.5 MB (also cvt staging)
    _Float16* wf  = (_Float16*)(w + 67108864);                    // 2 MB (4 weights)
    int* cnt    = (int*)(w + 69206016);
    int* fill   = (int*)(w + 69206016 + 16384);
    int* rowptr = (int*)(w + 69206016 + 32768);
    int* ecol   = (int*)(w + 69206016 + 65536);                   // 512 KB

    _Float16* stg = agg;   // cvt staging aliases agg (agg written later by attn)
    constexpr int WELEM = CH * CH;  // 262144

    cvtw_k<<<dim3(WELEM / (256 * 8), 4), 256, 0, stream>>>(Wq, Wk, Wv, Wfc, wf);

    zero_k<<<(L + 255) / 256, 256, 0, stream>>>(cnt, fill);
    count_k<<<(NE + 255) / 256, 256, 0, stream>>>(adj, cnt);
    scan_k<<<1, 64, 0, stream>>>(cnt, rowptr);
    scatter_k<<<(NE + 255) / 256, 256, 0, stream>>>(adj, rowptr, fill, ecol);

    dim3 gg(1024);  // (M/128)*(N/128) = 256*4
    cvt8_k<<<M_ROWS * CH / (256 * 8), 256, 0, stream>>>(queries, stg);
    gemm_f16<false><<<gg, 256, 0, stream>>>(stg, wf + 0 * WELEM, bq, qb);
    cvt8_k<<<M_ROWS * CH / (256 * 8), 256, 0, stream>>>(keys, stg);
    gemm_f16<false><<<gg, 256, 0, stream>>>(stg, wf + 1 * WELEM, bk, kb);
    cvt8_k<<<M_ROWS * CH / (256 * 8), 256, 0, stream>>>(values, stg);
    gemm_f16<false><<<gg, 256, 0, stream>>>(stg, wf + 2 * WELEM, bv, vb);

    attn_k<<<dim3(2 * NB * L), 256, 0, stream>>>(qb, kb, vb, rowptr, ecol, agg);
    // grid = 2(hg) * 8(n) * 4096(i) = 65536 blocks

    gemm_f16<true><<<gg, 256, 0, stream>>>(agg, wf + 3 * WELEM, bfc, (float*)d_out);
}

// Round 10
// 364.657 us; speedup vs baseline: 1.2563x; 1.0193x over previous
//
#include <hip/hip_runtime.h>
#include <cstdint>

typedef __attribute__((ext_vector_type(8))) short short8;
typedef __attribute__((ext_vector_type(8))) _Float16 half8;
typedef __attribute__((ext_vector_type(2))) _Float16 h2;
typedef __attribute__((ext_vector_type(2))) __fp16 fp16x2;
typedef __attribute__((ext_vector_type(4))) float f32x4;

#define AS1 __attribute__((address_space(1)))
#define AS3 __attribute__((address_space(3)))

constexpr int NB   = 8;
constexpr int L    = 4096;
constexpr int CH   = 512;     // model dim == E_IN
constexpr int DD   = 64;
constexpr int NE   = 131072;
constexpr int M_ROWS = NB * L;  // 32768

// VALU-pipe lane reduce (no DS ops)
template <int CTRL>
__device__ __forceinline__ float dppadd(float s) {
    union { float f; int i; } u, r;
    u.f = s;
    r.i = __builtin_amdgcn_update_dpp(0, u.i, CTRL, 0xF, 0xF, true);
    return s + r.f;
}

// ---------------- f32 -> f16 convert kernels (packed cvt_pkrtz) ----------------
__global__ __launch_bounds__(256)
void cvt8_k(const float* __restrict__ src, _Float16* __restrict__ dst) {
    const int i = blockIdx.x * 256 + threadIdx.x;   // one per 8 elems
    const f32x4 a = ((const f32x4*)src)[i * 2];
    const f32x4 b = ((const f32x4*)src)[i * 2 + 1];
    fp16x2 h[4];
    h[0] = __builtin_amdgcn_cvt_pkrtz(a.x, a.y);
    h[1] = __builtin_amdgcn_cvt_pkrtz(a.z, a.w);
    h[2] = __builtin_amdgcn_cvt_pkrtz(b.x, b.y);
    h[3] = __builtin_amdgcn_cvt_pkrtz(b.z, b.w);
    half8 out;
    __builtin_memcpy(&out, h, 16);
    ((half8*)dst)[i] = out;
}

__global__ __launch_bounds__(256)
void cvtw_k(const float* __restrict__ s0, const float* __restrict__ s1,
            const float* __restrict__ s2, const float* __restrict__ s3,
            _Float16* __restrict__ dst) {
    const float* s = (blockIdx.y == 0) ? s0 : (blockIdx.y == 1) ? s1
                   : (blockIdx.y == 2) ? s2 : s3;
    _Float16* d = dst + (size_t)blockIdx.y * (CH * CH);
    const int i = blockIdx.x * 256 + threadIdx.x;
    const f32x4 a = ((const f32x4*)s)[i * 2];
    const f32x4 b = ((const f32x4*)s)[i * 2 + 1];
    fp16x2 h[4];
    h[0] = __builtin_amdgcn_cvt_pkrtz(a.x, a.y);
    h[1] = __builtin_amdgcn_cvt_pkrtz(a.z, a.w);
    h[2] = __builtin_amdgcn_cvt_pkrtz(b.x, b.y);
    h[3] = __builtin_amdgcn_cvt_pkrtz(b.z, b.w);
    half8 out;
    __builtin_memcpy(&out, h, 16);
    ((half8*)d)[i] = out;
}

// ---------------- f16 B^T GEMM (round-3 proven structure) ----------------
template <bool OUT_F32>
__global__ __launch_bounds__(256)
void gemm_f16(const _Float16* __restrict__ A, const _Float16* __restrict__ B,
              const float* __restrict__ bias, void* __restrict__ Cp)
{
    __shared__ _Float16 As[128 * 64];
    __shared__ _Float16 Bs[128 * 64];
    const int bid = blockIdx.x;                     // 1024 blocks
    const int swz = (bid & 7) * 128 + (bid >> 3);   // bijective XCD swizzle
    const int row0 = (swz >> 2) * 128;
    const int col0 = (swz & 3) * 128;
    const int t = threadIdx.x, lane = t & 63, wid = t >> 6;
    const int wm = (wid >> 1) * 64, wn = (wid & 1) * 64;
    const int fr = lane & 15, fkb = (lane >> 4) * 8;
    const int srow = lane >> 3;
    const int scol = (lane & 7) * 8;

    f32x4 acc[4][4] = {};

    for (int k0 = 0; k0 < CH; k0 += 64) {
#pragma unroll
        for (int q = 0; q < 4; q++) {
            const int r = wid * 32 + q * 8;
            __builtin_amdgcn_global_load_lds(
                (const AS1 unsigned int*)
                    (A + (size_t)(row0 + r + srow) * CH + k0 + scol),
                (AS3 unsigned int*)(As + r * 64), 16, 0, 0);
        }
#pragma unroll
        for (int q = 0; q < 4; q++) {
            const int r = wid * 32 + q * 8;
            __builtin_amdgcn_global_load_lds(
                (const AS1 unsigned int*)
                    (B + (size_t)(col0 + r + srow) * CH + k0 + scol),
                (AS3 unsigned int*)(Bs + r * 64), 16, 0, 0);
        }
        __syncthreads();
#pragma unroll
        for (int kk = 0; kk < 2; kk++) {
            half8 afr[4], bfr[4];
#pragma unroll
            for (int f = 0; f < 4; f++)
                afr[f] = *(const half8*)&As[(wm + f * 16 + fr) * 64 + kk * 32 + fkb];
#pragma unroll
            for (int f = 0; f < 4; f++)
                bfr[f] = *(const half8*)&Bs[(wn + f * 16 + fr) * 64 + kk * 32 + fkb];
#pragma unroll
            for (int fm = 0; fm < 4; fm++)
#pragma unroll
                for (int fn = 0; fn < 4; fn++)
                    acc[fm][fn] = __builtin_amdgcn_mfma_f32_16x16x32_f16(
                        afr[fm], bfr[fn], acc[fm][fn], 0, 0, 0);
        }
        __syncthreads();
    }

    const int rsub = (lane >> 4) * 4;
#pragma unroll
    for (int fn = 0; fn < 4; fn++) {
        const int gc = col0 + wn + fn * 16 + fr;
        const float bv = bias[gc];
#pragma unroll
        for (int fm = 0; fm < 4; fm++) {
            const int gr = row0 + wm + fm * 16 + rsub;
#pragma unroll
            for (int j = 0; j < 4; j++) {
                const float v = acc[fm][fn][j] + bv;
                if constexpr (OUT_F32)
                    ((float*)Cp)[(size_t)(gr + j) * CH + gc] = v;
                else
                    ((_Float16*)Cp)[(size_t)(gr + j) * CH + gc] = (_Float16)v;
            }
        }
    }
}

// ---------------- CSR build ----------------
__global__ void zero_k(int* cnt, int* fill) {
    int i = blockIdx.x * blockDim.x + threadIdx.x;
    if (i < L) { cnt[i] = 0; fill[i] = 0; }
}
__global__ void count_k(const int* __restrict__ adj, int* __restrict__ cnt) {
    int e = blockIdx.x * blockDim.x + threadIdx.x;
    if (e < NE) atomicAdd(&cnt[adj[e]], 1);
}
__global__ void scan_k(const int* __restrict__ cnt, int* __restrict__ rowptr) {
    const int lane = threadIdx.x;      // 64 threads, 1 wave
    const int base = lane * 64;
    int s = 0;
    for (int t2 = 0; t2 < 64; t2++) s += cnt[base + t2];
    int incl = s;
    for (int off = 1; off < 64; off <<= 1) {
        int v = __shfl_up(incl, off);
        if (lane >= off) incl += v;
    }
    int run = incl - s;   // exclusive prefix
    for (int t2 = 0; t2 < 64; t2++) { rowptr[base + t2] = run; run += cnt[base + t2]; }
    if (lane == 63) rowptr[L] = run;
}
__global__ void scatter_k(const int* __restrict__ adj, const int* __restrict__ rowptr,
                          int* __restrict__ fill, int* __restrict__ ecol) {
    int e = blockIdx.x * blockDim.x + threadIdx.x;
    if (e < NE) {
        int rr = adj[e];
        int pos = rowptr[rr] + atomicAdd(&fill[rr], 1);
        ecol[pos] = adj[NE + e];
    }
}

// ---------------- fused edge-softmax + SPMM ----------------
// Round-3 skeleton + full-rate 2xf16 math (v_dot2_f32_f16 K-dot, v_pk_fma_f16
// V-accum in f16) + 2-deep K/V load pipeline + DPP 8-lane reduce.
// block = (i, n, hg): 256 threads = 4 waves, wave w = head hg*4+w.
// XCD pinning: n = bid & 7 -> per-XCD live K/V slice = 4 MB = one L2.
// Wave: 8 groups x 8 lanes; one edge/group/iter, lane g holds dims g*8..+7.
__global__ __launch_bounds__(256)
void attn_k(const _Float16* __restrict__ qb, const _Float16* __restrict__ kb,
            const _Float16* __restrict__ vb, const int* __restrict__ rowptr,
            const int* __restrict__ ecol, _Float16* __restrict__ agg)
{
    __shared__ float part[4 * 8 * 65];   // [wave][grp][65] (stride 65: conflict-free)
    const int bid = blockIdx.x;
    const int n   = bid & 7;
    const int rem = bid >> 3;
    const int hg  = rem >> 12;          // 0 or 1
    const int i   = rem & 4095;
    const int lane = threadIdx.x & 63;
    const int w    = threadIdx.x >> 6;  // wave 0..3
    const int h    = hg * 4 + w;
    const int g    = lane & 7;          // dim-chunk within edge
    const int grp  = lane >> 3;         // edge slot 0..7
    const size_t rowbase = ((size_t)(n * L + i)) * CH + h * DD;

    // Q fragment as f16 pairs, pre-scaled by 1/sqrt(64)*log2(e)
    fp16x2 qq[4];
    {
        const half8 qu = *(const half8*)(qb + rowbase + g * 8);
        const _Float16 sc = (_Float16)(0.125f * 1.44269504088896f);
        h2 qh[4];
#pragma unroll
        for (int e = 0; e < 4; e++) {
            qh[e][0] = qu[2 * e] * sc;
            qh[e][1] = qu[2 * e + 1] * sc;
        }
        __builtin_memcpy(qq, qh, 16);
    }
    const int start = rowptr[i], end = rowptr[i + 1];
    // wave-uniform bases; per-lane 32-bit byte offset (j<<10 | g<<4)
    const char* kb_u = (const char*)(kb + (size_t)n * L * CH + h * DD);
    const char* vb_u = (const char*)(vb + (size_t)n * L * CH + h * DD);
    const int goff = g << 4;

    h2 o2[4] = {};
    float lsum = 0.f;

    const int nIter = (end - start + 7) >> 3;
    int idx = start + grp;
    const int last = end - 1;
    half8 k0{}, v0{}, k1{}, v1{};
    int jC = 0;
    if (nIter > 0) {
        const int jA = ecol[min(idx, last)];
        const int jB = ecol[min(idx + 8, last)];
        k0 = *(const half8*)(kb_u + ((jA << 10) + goff));
        v0 = *(const half8*)(vb_u + ((jA << 10) + goff));
        jC = ecol[min(idx + 16, last)];
        k1 = *(const half8*)(kb_u + ((jB << 10) + goff));
        v1 = *(const half8*)(vb_u + ((jB << 10) + goff));
    }

#pragma unroll 2
    for (int it = 0; it < nIter; ++it) {
        // issue iter+2's K/V loads and iter+3's index first
        const half8 kn = *(const half8*)(kb_u + ((jC << 10) + goff));
        const half8 vn = *(const half8*)(vb_u + ((jC << 10) + goff));
        const int jn = ecol[min(idx + 24, last)];
        const bool valid = idx < end;
        // K-dot via v_dot2_f32_f16 (2 MACs/instr, f32 accum)
        fp16x2 kk[4];
        __builtin_memcpy(kk, &k0, 16);
        float s = 0.f;
#if __has_builtin(__builtin_amdgcn_fdot2)
#pragma unroll
        for (int e = 0; e < 4; e++)
            s = __builtin_amdgcn_fdot2(kk[e], qq[e], s, false);
#else
#pragma unroll
        for (int e = 0; e < 4; e++) {
            s = fmaf((float)kk[e][0], (float)qq[e][0], s);
            s = fmaf((float)kk[e][1], (float)qq[e][1], s);
        }
#endif
        s = dppadd<0xB1>(s);    // + lane^1
        s = dppadd<0x4E>(s);    // + lane^2
        s = dppadd<0x141>(s);   // + half-row mirror (completes 8-lane sum)
        float pe = exp2f(s);
        pe = valid ? pe : 0.f;
        // V-accum via v_pk_fma_f16 (f16 accumulators; output normalized later)
        const _Float16 ph = (_Float16)pe;
        const h2 pe2 = {ph, ph};
        h2 vv[4];
        __builtin_memcpy(vv, &v0, 16);
#pragma unroll
        for (int e = 0; e < 4; e++)
            o2[e] += pe2 * vv[e];
        lsum += pe;
        // rotate pipeline
        k0 = k1; v0 = v1; k1 = kn; v1 = vn; jC = jn; idx += 8;
    }

    // total lsum across the 8 groups (uniform within a group)
    lsum += __shfl_xor(lsum, 8);
    lsum += __shfl_xor(lsum, 16);
    lsum += __shfl_xor(lsum, 32);

    // merge o across groups via per-wave LDS transpose (f32)
    float o[8];
#pragma unroll
    for (int e = 0; e < 4; e++) {
        o[2 * e]     = (float)o2[e][0];
        o[2 * e + 1] = (float)o2[e][1];
    }
    float* p = part + w * (8 * 65);
    float* pw = p + grp * 65 + g * 8;
    *(f32x4*)(pw)     = *(f32x4*)&o[0];
    *(f32x4*)(pw + 4) = *(f32x4*)&o[4];
    __builtin_amdgcn_s_waitcnt(0);  // lgkm drain (same-wave LDS RAW)
    float osum = 0.f;
#pragma unroll
    for (int gg = 0; gg < 8; gg++)
        osum += p[gg * 65 + lane];

    const float inv = (end > start) ? 1.f / lsum : 0.f;
    agg[rowbase + lane] = (_Float16)(osum * inv);
}

extern "C" void kernel_launch(void* const* d_in, const int* in_sizes, int n_in,
                              void* d_out, int out_size, void* d_ws, size_t ws_size,
                              hipStream_t stream)
{
    (void)in_sizes; (void)n_in; (void)out_size; (void)ws_size;
    const float* queries = (const float*)d_in[0];
    const float* keys    = (const float*)d_in[1];
    const float* values  = (const float*)d_in[2];
    const int*   adj     = (const int*)d_in[3];
    const float* Wq  = (const float*)d_in[4];
    const float* bq  = (const float*)d_in[5];
    const float* Wk  = (const float*)d_in[6];
    const float* bk  = (const float*)d_in[7];
    const float* Wv  = (const float*)d_in[8];
    const float* bv  = (const float*)d_in[9];
    const float* Wfc = (const float*)d_in[10];
    const float* bfc = (const float*)d_in[11];

    // q/k f16 projections live inside d_out (dead before final GEMM writes it)
    _Float16* qb = (_Float16*)d_out;                   // 33.5 MB
    _Float16* kb = qb + (size_t)M_ROWS * CH;           // 33.5 MB
    uint8_t* w = (uint8_t*)d_ws;
    _Float16* vb  = (_Float16*)(w);                               // 33.5 MB
    _Float16* agg = (_Float16*)(w + 33554432);                    // 33.5 MB (also cvt staging)
    _Float16* wf  = (_Float16*)(w + 67108864);                    // 2 MB (4 weights)
    int* cnt    = (int*)(w + 69206016);
    int* fill   = (int*)(w + 69206016 + 16384);
    int* rowptr = (int*)(w + 69206016 + 32768);
    int* ecol   = (int*)(w + 69206016 + 65536);                   // 512 KB

    _Float16* stg = agg;   // cvt staging aliases agg (agg written later by attn)
    constexpr int WELEM = CH * CH;  // 262144

    cvtw_k<<<dim3(WELEM / (256 * 8), 4), 256, 0, stream>>>(Wq, Wk, Wv, Wfc, wf);

    zero_k<<<(L + 255) / 256, 256, 0, stream>>>(cnt, fill);
    count_k<<<(NE + 255) / 256, 256, 0, stream>>>(adj, cnt);
    scan_k<<<1, 64, 0, stream>>>(cnt, rowptr);
    scatter_k<<<(NE + 255) / 256, 256, 0, stream>>>(adj, rowptr, fill, ecol);

    dim3 gg(1024);  // (M/128)*(N/128) = 256*4
    cvt8_k<<<M_ROWS * CH / (256 * 8), 256, 0, stream>>>(queries, stg);
    gemm_f16<false><<<gg, 256, 0, stream>>>(stg, wf + 0 * WELEM, bq, qb);
    cvt8_k<<<M_ROWS * CH / (256 * 8), 256, 0, stream>>>(keys, stg);
    gemm_f16<false><<<gg, 256, 0, stream>>>(stg, wf + 1 * WELEM, bk, kb);
    cvt8_k<<<M_ROWS * CH / (256 * 8), 256, 0, stream>>>(values, stg);
    gemm_f16<false><<<gg, 256, 0, stream>>>(stg, wf + 2 * WELEM, bv, vb);

    attn_k<<<dim3(2 * NB * L), 256, 0, stream>>>(qb, kb, vb, rowptr, ecol, agg);
    // grid = 2(hg) * 8(n) * 4096(i) = 65536 blocks

    gemm_f16<true><<<gg, 256, 0, stream>>>(agg, wf + 3 * WELEM, bfc, (float*)d_out);
}

// Round 11
// 344.789 us; speedup vs baseline: 1.3287x; 1.0576x over previous
//
#include <hip/hip_runtime.h>
#include <cstdint>

typedef __attribute__((ext_vector_type(8))) short short8;
typedef __attribute__((ext_vector_type(8))) _Float16 half8;
typedef __attribute__((ext_vector_type(2))) _Float16 h2;
typedef __attribute__((ext_vector_type(2))) __fp16 fp16x2;
typedef __attribute__((ext_vector_type(4))) float f32x4;

#define AS1 __attribute__((address_space(1)))
#define AS3 __attribute__((address_space(3)))

constexpr int NB   = 8;
constexpr int L    = 4096;
constexpr int CH   = 512;     // model dim == E_IN
constexpr int DD   = 64;
constexpr int NE   = 131072;
constexpr int M_ROWS = NB * L;  // 32768

// VALU-pipe lane reduce (no DS ops)
template <int CTRL>
__device__ __forceinline__ float dppadd(float s) {
    union { float f; int i; } u, r;
    u.f = s;
    r.i = __builtin_amdgcn_update_dpp(0, u.i, CTRL, 0xF, 0xF, true);
    return s + r.f;
}

// ---------------- f32 -> f16 convert kernels (packed cvt_pkrtz) ----------------
__global__ __launch_bounds__(256)
void cvt8_k(const float* __restrict__ src, _Float16* __restrict__ dst) {
    const int i = blockIdx.x * 256 + threadIdx.x;   // one per 8 elems
    const f32x4 a = ((const f32x4*)src)[i * 2];
    const f32x4 b = ((const f32x4*)src)[i * 2 + 1];
    fp16x2 h[4];
    h[0] = __builtin_amdgcn_cvt_pkrtz(a.x, a.y);
    h[1] = __builtin_amdgcn_cvt_pkrtz(a.z, a.w);
    h[2] = __builtin_amdgcn_cvt_pkrtz(b.x, b.y);
    h[3] = __builtin_amdgcn_cvt_pkrtz(b.z, b.w);
    half8 out;
    __builtin_memcpy(&out, h, 16);
    ((half8*)dst)[i] = out;
}

__global__ __launch_bounds__(256)
void cvtw_k(const float* __restrict__ s0, const float* __restrict__ s1,
            const float* __restrict__ s2, const float* __restrict__ s3,
            _Float16* __restrict__ dst) {
    const float* s = (blockIdx.y == 0) ? s0 : (blockIdx.y == 1) ? s1
                   : (blockIdx.y == 2) ? s2 : s3;
    _Float16* d = dst + (size_t)blockIdx.y * (CH * CH);
    const int i = blockIdx.x * 256 + threadIdx.x;
    const f32x4 a = ((const f32x4*)s)[i * 2];
    const f32x4 b = ((const f32x4*)s)[i * 2 + 1];
    fp16x2 h[4];
    h[0] = __builtin_amdgcn_cvt_pkrtz(a.x, a.y);
    h[1] = __builtin_amdgcn_cvt_pkrtz(a.z, a.w);
    h[2] = __builtin_amdgcn_cvt_pkrtz(b.x, b.y);
    h[3] = __builtin_amdgcn_cvt_pkrtz(b.z, b.w);
    half8 out;
    __builtin_memcpy(&out, h, 16);
    ((half8*)d)[i] = out;
}

// ---------------- f16 B^T GEMM (round-3 proven structure) ----------------
template <bool OUT_F32>
__global__ __launch_bounds__(256)
void gemm_f16(const _Float16* __restrict__ A, const _Float16* __restrict__ B,
              const float* __restrict__ bias, void* __restrict__ Cp)
{
    __shared__ _Float16 As[128 * 64];
    __shared__ _Float16 Bs[128 * 64];
    const int bid = blockIdx.x;                     // 1024 blocks
    const int swz = (bid & 7) * 128 + (bid >> 3);   // bijective XCD swizzle
    const int row0 = (swz >> 2) * 128;
    const int col0 = (swz & 3) * 128;
    const int t = threadIdx.x, lane = t & 63, wid = t >> 6;
    const int wm = (wid >> 1) * 64, wn = (wid & 1) * 64;
    const int fr = lane & 15, fkb = (lane >> 4) * 8;
    const int srow = lane >> 3;
    const int scol = (lane & 7) * 8;

    f32x4 acc[4][4] = {};

    for (int k0 = 0; k0 < CH; k0 += 64) {
#pragma unroll
        for (int q = 0; q < 4; q++) {
            const int r = wid * 32 + q * 8;
            __builtin_amdgcn_global_load_lds(
                (const AS1 unsigned int*)
                    (A + (size_t)(row0 + r + srow) * CH + k0 + scol),
                (AS3 unsigned int*)(As + r * 64), 16, 0, 0);
        }
#pragma unroll
        for (int q = 0; q < 4; q++) {
            const int r = wid * 32 + q * 8;
            __builtin_amdgcn_global_load_lds(
                (const AS1 unsigned int*)
                    (B + (size_t)(col0 + r + srow) * CH + k0 + scol),
                (AS3 unsigned int*)(Bs + r * 64), 16, 0, 0);
        }
        __syncthreads();
#pragma unroll
        for (int kk = 0; kk < 2; kk++) {
            half8 afr[4], bfr[4];
#pragma unroll
            for (int f = 0; f < 4; f++)
                afr[f] = *(const half8*)&As[(wm + f * 16 + fr) * 64 + kk * 32 + fkb];
#pragma unroll
            for (int f = 0; f < 4; f++)
                bfr[f] = *(const half8*)&Bs[(wn + f * 16 + fr) * 64 + kk * 32 + fkb];
#pragma unroll
            for (int fm = 0; fm < 4; fm++)
#pragma unroll
                for (int fn = 0; fn < 4; fn++)
                    acc[fm][fn] = __builtin_amdgcn_mfma_f32_16x16x32_f16(
                        afr[fm], bfr[fn], acc[fm][fn], 0, 0, 0);
        }
        __syncthreads();
    }

    const int rsub = (lane >> 4) * 4;
#pragma unroll
    for (int fn = 0; fn < 4; fn++) {
        const int gc = col0 + wn + fn * 16 + fr;
        const float bv = bias[gc];
#pragma unroll
        for (int fm = 0; fm < 4; fm++) {
            const int gr = row0 + wm + fm * 16 + rsub;
#pragma unroll
            for (int j = 0; j < 4; j++) {
                const float v = acc[fm][fn][j] + bv;
                if constexpr (OUT_F32)
                    ((float*)Cp)[(size_t)(gr + j) * CH + gc] = v;
                else
                    ((_Float16*)Cp)[(size_t)(gr + j) * CH + gc] = (_Float16)v;
            }
        }
    }
}

// ---------------- CSR build ----------------
__global__ void zero_k(int* cnt, int* fill) {
    int i = blockIdx.x * blockDim.x + threadIdx.x;
    if (i < L) { cnt[i] = 0; fill[i] = 0; }
}
__global__ void count_k(const int* __restrict__ adj, int* __restrict__ cnt) {
    int e = blockIdx.x * blockDim.x + threadIdx.x;
    if (e < NE) atomicAdd(&cnt[adj[e]], 1);
}
__global__ void scan_k(const int* __restrict__ cnt, int* __restrict__ rowptr) {
    const int lane = threadIdx.x;      // 64 threads, 1 wave
    const int base = lane * 64;
    int s = 0;
    for (int t2 = 0; t2 < 64; t2++) s += cnt[base + t2];
    int incl = s;
    for (int off = 1; off < 64; off <<= 1) {
        int v = __shfl_up(incl, off);
        if (lane >= off) incl += v;
    }
    int run = incl - s;   // exclusive prefix
    for (int t2 = 0; t2 < 64; t2++) { rowptr[base + t2] = run; run += cnt[base + t2]; }
    if (lane == 63) rowptr[L] = run;
}
__global__ void scatter_k(const int* __restrict__ adj, const int* __restrict__ rowptr,
                          int* __restrict__ fill, int* __restrict__ ecol) {
    int e = blockIdx.x * blockDim.x + threadIdx.x;
    if (e < NE) {
        int rr = adj[e];
        int pos = rowptr[rr] + atomicAdd(&fill[rr], 1);
        ecol[pos] = adj[NE + e];
    }
}

// ---------------- fused edge-softmax + SPMM ----------------
// Round-10 skeleton widened to 2 edges/group/iter (A,B) with fully
// independent chains: 2 dot chains, 2 DPP reduces, 2 exps (TRANS overlaps),
// 2 accumulators (merged at end). 1-deep prefetch of next iter's 4 vectors.
// block = (i, n, hg): 256 threads = 4 waves, wave w = head hg*4+w.
// XCD pinning: n = bid & 7 -> per-XCD live K/V slice = 4 MB = one L2.
__global__ __launch_bounds__(256)
void attn_k(const _Float16* __restrict__ qb, const _Float16* __restrict__ kb,
            const _Float16* __restrict__ vb, const int* __restrict__ rowptr,
            const int* __restrict__ ecol, _Float16* __restrict__ agg)
{
    __shared__ float part[4 * 8 * 65];   // [wave][grp][65] (stride 65: conflict-free)
    const int bid = blockIdx.x;
    const int n   = bid & 7;
    const int rem = bid >> 3;
    const int hg  = rem >> 12;          // 0 or 1
    const int i   = rem & 4095;
    const int lane = threadIdx.x & 63;
    const int w    = threadIdx.x >> 6;  // wave 0..3
    const int h    = hg * 4 + w;
    const int g    = lane & 7;          // dim-chunk within edge
    const int grp  = lane >> 3;         // edge slot 0..7
    const size_t rowbase = ((size_t)(n * L + i)) * CH + h * DD;

    // Q fragment as f16 pairs, pre-scaled by 1/sqrt(64)*log2(e)
    fp16x2 qq[4];
    {
        const half8 qu = *(const half8*)(qb + rowbase + g * 8);
        const _Float16 sc = (_Float16)(0.125f * 1.44269504088896f);
        h2 qh[4];
#pragma unroll
        for (int e = 0; e < 4; e++) {
            qh[e][0] = qu[2 * e] * sc;
            qh[e][1] = qu[2 * e + 1] * sc;
        }
        __builtin_memcpy(qq, qh, 16);
    }
    const int start = rowptr[i], end = rowptr[i + 1];
    const char* kb_u = (const char*)(kb + (size_t)n * L * CH + h * DD);
    const char* vb_u = (const char*)(vb + (size_t)n * L * CH + h * DD);
    const int goff = g << 4;

    h2 oA[4] = {}, oB[4] = {};
    float lsA = 0.f, lsB = 0.f;

    const int nIt = (end - start + 15) >> 4;   // 16 edges per wave-iter
    int idx = start + grp;
    const int last = end - 1;
    half8 kA{}, vA{}, kB{}, vB{};
    int jA1 = 0, jB1 = 0;
    if (nIt > 0) {
        const int jA0 = ecol[min(idx, last)];
        const int jB0 = ecol[min(idx + 8, last)];
        kA = *(const half8*)(kb_u + ((jA0 << 10) + goff));
        vA = *(const half8*)(vb_u + ((jA0 << 10) + goff));
        kB = *(const half8*)(kb_u + ((jB0 << 10) + goff));
        vB = *(const half8*)(vb_u + ((jB0 << 10) + goff));
        jA1 = ecol[min(idx + 16, last)];
        jB1 = ecol[min(idx + 24, last)];
    }

    for (int it = 0; it < nIt; ++it) {
        // prefetch next iteration's 4 vectors + indices
        const half8 kAn = *(const half8*)(kb_u + ((jA1 << 10) + goff));
        const half8 vAn = *(const half8*)(vb_u + ((jA1 << 10) + goff));
        const half8 kBn = *(const half8*)(kb_u + ((jB1 << 10) + goff));
        const half8 vBn = *(const half8*)(vb_u + ((jB1 << 10) + goff));
        const int jA2 = ecol[min(idx + 32, last)];
        const int jB2 = ecol[min(idx + 40, last)];
        const bool vdA = idx < end;
        const bool vdB = idx + 8 < end;
        // two independent dot chains (v_dot2_f32_f16)
        fp16x2 ka[4], kb2[4];
        __builtin_memcpy(ka, &kA, 16);
        __builtin_memcpy(kb2, &kB, 16);
        float sA = 0.f, sB = 0.f;
#if __has_builtin(__builtin_amdgcn_fdot2)
#pragma unroll
        for (int e = 0; e < 4; e++) {
            sA = __builtin_amdgcn_fdot2(ka[e],  qq[e], sA, false);
            sB = __builtin_amdgcn_fdot2(kb2[e], qq[e], sB, false);
        }
#else
#pragma unroll
        for (int e = 0; e < 4; e++) {
            sA = fmaf((float)ka[e][0],  (float)qq[e][0], sA);
            sA = fmaf((float)ka[e][1],  (float)qq[e][1], sA);
            sB = fmaf((float)kb2[e][0], (float)qq[e][0], sB);
            sB = fmaf((float)kb2[e][1], (float)qq[e][1], sB);
        }
#endif
        sA = dppadd<0xB1>(sA);  sB = dppadd<0xB1>(sB);   // + lane^1
        sA = dppadd<0x4E>(sA);  sB = dppadd<0x4E>(sB);   // + lane^2
        sA = dppadd<0x141>(sA); sB = dppadd<0x141>(sB);  // + half-row mirror
        float peA = exp2f(sA); peA = vdA ? peA : 0.f;
        float peB = exp2f(sB); peB = vdB ? peB : 0.f;
        const _Float16 phA = (_Float16)peA, phB = (_Float16)peB;
        const h2 pa2 = {phA, phA}, pb2 = {phB, phB};
        h2 va2[4], vb2[4];
        __builtin_memcpy(va2, &vA, 16);
        __builtin_memcpy(vb2, &vB, 16);
#pragma unroll
        for (int e = 0; e < 4; e++) {
            oA[e] += pa2 * va2[e];   // v_pk_fma_f16, two independent chains
            oB[e] += pb2 * vb2[e];
        }
        lsA += peA; lsB += peB;
        // rotate pipeline
        kA = kAn; vA = vAn; kB = kBn; vB = vBn;
        jA1 = jA2; jB1 = jB2; idx += 16;
    }

    // total lsum across the 8 groups (uniform within a group)
    float lsum = lsA + lsB;
    lsum += __shfl_xor(lsum, 8);
    lsum += __shfl_xor(lsum, 16);
    lsum += __shfl_xor(lsum, 32);

    // merge oA+oB -> f32, then across groups via per-wave LDS transpose
    float o[8];
#pragma unroll
    for (int e = 0; e < 4; e++) {
        o[2 * e]     = (float)oA[e][0] + (float)oB[e][0];
        o[2 * e + 1] = (float)oA[e][1] + (float)oB[e][1];
    }
    float* p = part + w * (8 * 65);
    float* pw = p + grp * 65 + g * 8;
    *(f32x4*)(pw)     = *(f32x4*)&o[0];
    *(f32x4*)(pw + 4) = *(f32x4*)&o[4];
    __builtin_amdgcn_s_waitcnt(0);  // lgkm drain (same-wave LDS RAW)
    float osum = 0.f;
#pragma unroll
    for (int gg = 0; gg < 8; gg++)
        osum += p[gg * 65 + lane];

    const float inv = (end > start) ? 1.f / lsum : 0.f;
    agg[rowbase + lane] = (_Float16)(osum * inv);
}

extern "C" void kernel_launch(void* const* d_in, const int* in_sizes, int n_in,
                              void* d_out, int out_size, void* d_ws, size_t ws_size,
                              hipStream_t stream)
{
    (void)in_sizes; (void)n_in; (void)out_size; (void)ws_size;
    const float* queries = (const float*)d_in[0];
    const float* keys    = (const float*)d_in[1];
    const float* values  = (const float*)d_in[2];
    const int*   adj     = (const int*)d_in[3];
    const float* Wq  = (const float*)d_in[4];
    const float* bq  = (const float*)d_in[5];
    const float* Wk  = (const float*)d_in[6];
    const float* bk  = (const float*)d_in[7];
    const float* Wv  = (const float*)d_in[8];
    const float* bv  = (const float*)d_in[9];
    const float* Wfc = (const float*)d_in[10];
    const float* bfc = (const float*)d_in[11];

    // q/k f16 projections live inside d_out (dead before final GEMM writes it)
    _Float16* qb = (_Float16*)d_out;                   // 33.5 MB
    _Float16* kb = qb + (size_t)M_ROWS * CH;           // 33.5 MB
    uint8_t* w = (uint8_t*)d_ws;
    _Float16* vb  = (_Float16*)(w);                               // 33.5 MB
    _Float16* agg = (_Float16*)(w + 33554432);                    // 33.5 MB (also cvt staging)
    _Float16* wf  = (_Float16*)(w + 67108864);                    // 2 MB (4 weights)
    int* cnt    = (int*)(w + 69206016);
    int* fill   = (int*)(w + 69206016 + 16384);
    int* rowptr = (int*)(w + 69206016 + 32768);
    int* ecol   = (int*)(w + 69206016 + 65536);                   // 512 KB

    _Float16* stg = agg;   // cvt staging aliases agg (agg written later by attn)
    constexpr int WELEM = CH * CH;  // 262144

    cvtw_k<<<dim3(WELEM / (256 * 8), 4), 256, 0, stream>>>(Wq, Wk, Wv, Wfc, wf);

    zero_k<<<(L + 255) / 256, 256, 0, stream>>>(cnt, fill);
    count_k<<<(NE + 255) / 256, 256, 0, stream>>>(adj, cnt);
    scan_k<<<1, 64, 0, stream>>>(cnt, rowptr);
    scatter_k<<<(NE + 255) / 256, 256, 0, stream>>>(adj, rowptr, fill, ecol);

    dim3 gg(1024);  // (M/128)*(N/128) = 256*4
    cvt8_k<<<M_ROWS * CH / (256 * 8), 256, 0, stream>>>(queries, stg);
    gemm_f16<false><<<gg, 256, 0, stream>>>(stg, wf + 0 * WELEM, bq, qb);
    cvt8_k<<<M_ROWS * CH / (256 * 8), 256, 0, stream>>>(keys, stg);
    gemm_f16<false><<<gg, 256, 0, stream>>>(stg, wf + 1 * WELEM, bk, kb);
    cvt8_k<<<M_ROWS * CH / (256 * 8), 256, 0, stream>>>(values, stg);
    gemm_f16<false><<<gg, 256, 0, stream>>>(stg, wf + 2 * WELEM, bv, vb);

    attn_k<<<dim3(2 * NB * L), 256, 0, stream>>>(qb, kb, vb, rowptr, ecol, agg);
    // grid = 2(hg) * 8(n) * 4096(i) = 65536 blocks

    gemm_f16<true><<<gg, 256, 0, stream>>>(agg, wf + 3 * WELEM, bfc, (float*)d_out);
}

// Round 12
// 307.532 us; speedup vs baseline: 1.4897x; 1.1211x over previous
//
#include <hip/hip_runtime.h>
#include <cstdint>

typedef __attribute__((ext_vector_type(8))) short short8;
typedef __attribute__((ext_vector_type(8))) _Float16 half8;
typedef __attribute__((ext_vector_type(2))) _Float16 h2;
typedef __attribute__((ext_vector_type(2))) __fp16 fp16x2;
typedef __attribute__((ext_vector_type(4))) float f32x4;

#define AS1 __attribute__((address_space(1)))
#define AS3 __attribute__((address_space(3)))

constexpr int NB   = 8;
constexpr int L    = 4096;
constexpr int CH   = 512;     // model dim == E_IN
constexpr int DD   = 64;
constexpr int NE   = 131072;
constexpr int M_ROWS = NB * L;  // 32768
constexpr int WELEM  = CH * CH; // 262144

// VALU-pipe lane reduce (no DS ops)
template <int CTRL>
__device__ __forceinline__ float dppadd(float s) {
    union { float f; int i; } u, r;
    u.f = s;
    r.i = __builtin_amdgcn_update_dpp(0, u.i, CTRL, 0xF, 0xF, true);
    return s + r.f;
}

// ---------------- device bodies (shared by fused + standalone kernels) -------

// f32 -> f16, 8 elems per thread (bid covers 256*8 elems)
__device__ __forceinline__ void cvt_body(int bid, const float* __restrict__ src,
                                         _Float16* __restrict__ dst) {
    const int i = bid * 256 + (int)threadIdx.x;
    const f32x4 a = ((const f32x4*)src)[i * 2];
    const f32x4 b = ((const f32x4*)src)[i * 2 + 1];
    fp16x2 h[4];
    h[0] = __builtin_amdgcn_cvt_pkrtz(a.x, a.y);
    h[1] = __builtin_amdgcn_cvt_pkrtz(a.z, a.w);
    h[2] = __builtin_amdgcn_cvt_pkrtz(b.x, b.y);
    h[3] = __builtin_amdgcn_cvt_pkrtz(b.z, b.w);
    half8 out;
    __builtin_memcpy(&out, h, 16);
    ((half8*)dst)[i] = out;
}

// f16 B^T GEMM body (round-3/11 proven structure).
// LDS passed in so fused kernels declare it once.
template <bool OUT_F32>
__device__ __forceinline__ void gemm_body(int bid, _Float16* As, _Float16* Bs,
                                          const _Float16* __restrict__ A,
                                          const _Float16* __restrict__ B,
                                          const float* __restrict__ bias,
                                          void* __restrict__ Cp)
{
    const int swz = (bid & 7) * 128 + (bid >> 3);   // bijective XCD swizzle
    const int row0 = (swz >> 2) * 128;
    const int col0 = (swz & 3) * 128;
    const int t = threadIdx.x, lane = t & 63, wid = t >> 6;
    const int wm = (wid >> 1) * 64, wn = (wid & 1) * 64;
    const int fr = lane & 15, fkb = (lane >> 4) * 8;
    const int srow = lane >> 3;
    const int scol = (lane & 7) * 8;

    f32x4 acc[4][4] = {};

    for (int k0 = 0; k0 < CH; k0 += 64) {
#pragma unroll
        for (int q = 0; q < 4; q++) {
            const int r = wid * 32 + q * 8;
            __builtin_amdgcn_global_load_lds(
                (const AS1 unsigned int*)
                    (A + (size_t)(row0 + r + srow) * CH + k0 + scol),
                (AS3 unsigned int*)(As + r * 64), 16, 0, 0);
        }
#pragma unroll
        for (int q = 0; q < 4; q++) {
            const int r = wid * 32 + q * 8;
            __builtin_amdgcn_global_load_lds(
                (const AS1 unsigned int*)
                    (B + (size_t)(col0 + r + srow) * CH + k0 + scol),
                (AS3 unsigned int*)(Bs + r * 64), 16, 0, 0);
        }
        __syncthreads();
#pragma unroll
        for (int kk = 0; kk < 2; kk++) {
            half8 afr[4], bfr[4];
#pragma unroll
            for (int f = 0; f < 4; f++)
                afr[f] = *(const half8*)&As[(wm + f * 16 + fr) * 64 + kk * 32 + fkb];
#pragma unroll
            for (int f = 0; f < 4; f++)
                bfr[f] = *(const half8*)&Bs[(wn + f * 16 + fr) * 64 + kk * 32 + fkb];
#pragma unroll
            for (int fm = 0; fm < 4; fm++)
#pragma unroll
                for (int fn = 0; fn < 4; fn++)
                    acc[fm][fn] = __builtin_amdgcn_mfma_f32_16x16x32_f16(
                        afr[fm], bfr[fn], acc[fm][fn], 0, 0, 0);
        }
        __syncthreads();
    }

    const int rsub = (lane >> 4) * 4;
#pragma unroll
    for (int fn = 0; fn < 4; fn++) {
        const int gc = col0 + wn + fn * 16 + fr;
        const float bv = bias[gc];
#pragma unroll
        for (int fm = 0; fm < 4; fm++) {
            const int gr = row0 + wm + fm * 16 + rsub;
#pragma unroll
            for (int j = 0; j < 4; j++) {
                const float v = acc[fm][fn][j] + bv;
                if constexpr (OUT_F32)
                    ((float*)Cp)[(size_t)(gr + j) * CH + gc] = v;
                else
                    ((_Float16*)Cp)[(size_t)(gr + j) * CH + gc] = (_Float16)v;
            }
        }
    }
}

// weight convert: idx over 4*WELEM/8 groups, picks source by idx>>15
__device__ __forceinline__ void cvtw_body(int bid, const float* s0, const float* s1,
                                          const float* s2, const float* s3,
                                          _Float16* dst) {
    const int idx = bid * 256 + (int)threadIdx.x;   // 0 .. 131071
    const int wsel = idx >> 15;
    const float* s = (wsel == 0) ? s0 : (wsel == 1) ? s1 : (wsel == 2) ? s2 : s3;
    const int i = idx & 32767;
    const f32x4 a = ((const f32x4*)s)[i * 2];
    const f32x4 b = ((const f32x4*)s)[i * 2 + 1];
    fp16x2 h[4];
    h[0] = __builtin_amdgcn_cvt_pkrtz(a.x, a.y);
    h[1] = __builtin_amdgcn_cvt_pkrtz(a.z, a.w);
    h[2] = __builtin_amdgcn_cvt_pkrtz(b.x, b.y);
    h[3] = __builtin_amdgcn_cvt_pkrtz(b.z, b.w);
    half8 out;
    __builtin_memcpy(&out, h, 16);
    ((half8*)(dst + (size_t)wsel * WELEM))[i] = out;
}

__device__ __forceinline__ void zero_body(int bid, int* cnt, int* fill) {
    const int i = bid * 256 + (int)threadIdx.x;
    if (i < L) { cnt[i] = 0; fill[i] = 0; }
}
__device__ __forceinline__ void count_body(int bid, const int* adj, int* cnt) {
    const int e = bid * 256 + (int)threadIdx.x;
    if (e < NE) atomicAdd(&cnt[adj[e]], 1);
}
__device__ __forceinline__ void scan_body(const int* cnt, int* rowptr) {
    const int lane = threadIdx.x;      // first wave only
    if (lane >= 64) return;
    const int base = lane * 64;
    int s = 0;
    for (int t2 = 0; t2 < 64; t2++) s += cnt[base + t2];
    int incl = s;
    for (int off = 1; off < 64; off <<= 1) {
        int v = __shfl_up(incl, off);
        if (lane >= off) incl += v;
    }
    int run = incl - s;   // exclusive prefix
    for (int t2 = 0; t2 < 64; t2++) { rowptr[base + t2] = run; run += cnt[base + t2]; }
    if (lane == 63) rowptr[L] = run;
}
__device__ __forceinline__ void scatter_body(int bid, const int* adj, const int* rowptr,
                                             int* fill, int* ecol) {
    const int e = bid * 256 + (int)threadIdx.x;
    if (e < NE) {
        int rr = adj[e];
        int pos = rowptr[rr] + atomicAdd(&fill[rr], 1);
        ecol[pos] = adj[NE + e];
    }
}

// ---------------- fused dispatches (overlap path) ----------------
// D0: cvtQ(8192) | cvtw(512) | zero(16)
__global__ __launch_bounds__(256)
void fusedD0(const float* __restrict__ queries, _Float16* __restrict__ stgA,
             const float* Wq, const float* Wk, const float* Wv, const float* Wfc,
             _Float16* __restrict__ wf, int* cnt, int* fill)
{
    const int bid = blockIdx.x;
    if (bid < 8192)       cvt_body(bid, queries, stgA);
    else if (bid < 8704)  cvtw_body(bid - 8192, Wq, Wk, Wv, Wfc, wf);
    else                  zero_body(bid - 8704, cnt, fill);
}

// D1: gemmQ(1024) | cvtK(8192) | count(512)
__global__ __launch_bounds__(256)
void fusedD1(const _Float16* __restrict__ stgA, const _Float16* __restrict__ wf,
             const float* __restrict__ bq, _Float16* __restrict__ qb,
             const float* __restrict__ keys, _Float16* __restrict__ stgB,
             const int* __restrict__ adj, int* cnt)
{
    __shared__ _Float16 As[128 * 64];
    __shared__ _Float16 Bs[128 * 64];
    const int bid = blockIdx.x;
    if (bid < 1024)       gemm_body<false>(bid, As, Bs, stgA, wf, bq, qb);
    else if (bid < 9216)  cvt_body(bid - 1024, keys, stgB);
    else                  count_body(bid - 9216, adj, cnt);
}

// D2: gemmK(1024) | cvtV(8192) | scan(1)
__global__ __launch_bounds__(256)
void fusedD2(const _Float16* __restrict__ stgB, const _Float16* __restrict__ wf,
             const float* __restrict__ bk, _Float16* __restrict__ kb,
             const float* __restrict__ values, _Float16* __restrict__ stgA,
             const int* __restrict__ cnt, int* rowptr)
{
    __shared__ _Float16 As[128 * 64];
    __shared__ _Float16 Bs[128 * 64];
    const int bid = blockIdx.x;
    if (bid < 1024)       gemm_body<false>(bid, As, Bs, stgB, wf, bk, kb);
    else if (bid < 9216)  cvt_body(bid - 1024, values, stgA);
    else                  scan_body(cnt, rowptr);
}

// D3: gemmV(1024) | scatter(512)
__global__ __launch_bounds__(256)
void fusedD3(const _Float16* __restrict__ stgA, const _Float16* __restrict__ wf,
             const float* __restrict__ bv, _Float16* __restrict__ vb,
             const int* __restrict__ adj, const int* __restrict__ rowptr,
             int* fill, int* ecol)
{
    __shared__ _Float16 As[128 * 64];
    __shared__ _Float16 Bs[128 * 64];
    const int bid = blockIdx.x;
    if (bid < 1024)  gemm_body<false>(bid, As, Bs, stgA, wf, bv, vb);
    else             scatter_body(bid - 1024, adj, rowptr, fill, ecol);
}

// ---------------- standalone kernels (serial fallback + shared) ----------------
__global__ __launch_bounds__(256)
void cvt8_k(const float* __restrict__ src, _Float16* __restrict__ dst) {
    cvt_body(blockIdx.x, src, dst);
}
__global__ __launch_bounds__(256)
void cvtw_k(const float* Wq, const float* Wk, const float* Wv, const float* Wfc,
            _Float16* wf) {
    cvtw_body(blockIdx.x, Wq, Wk, Wv, Wfc, wf);
}
__global__ __launch_bounds__(256)
void zero_k(int* cnt, int* fill) { zero_body(blockIdx.x, cnt, fill); }
__global__ __launch_bounds__(256)
void count_k(const int* adj, int* cnt) { count_body(blockIdx.x, adj, cnt); }
__global__ __launch_bounds__(256)
void scan_k(const int* cnt, int* rowptr) { scan_body(cnt, rowptr); }
__global__ __launch_bounds__(256)
void scatter_k(const int* adj, const int* rowptr, int* fill, int* ecol) {
    scatter_body(blockIdx.x, adj, rowptr, fill, ecol);
}
template <bool OUT_F32>
__global__ __launch_bounds__(256)
void gemm_f16(const _Float16* __restrict__ A, const _Float16* __restrict__ B,
              const float* __restrict__ bias, void* __restrict__ Cp)
{
    __shared__ _Float16 As[128 * 64];
    __shared__ _Float16 Bs[128 * 64];
    gemm_body<OUT_F32>(blockIdx.x, As, Bs, A, B, bias, Cp);
}

// ---------------- fused edge-softmax + SPMM (round-11, unchanged) ----------------
__global__ __launch_bounds__(256)
void attn_k(const _Float16* __restrict__ qb, const _Float16* __restrict__ kb,
            const _Float16* __restrict__ vb, const int* __restrict__ rowptr,
            const int* __restrict__ ecol, _Float16* __restrict__ agg)
{
    __shared__ float part[4 * 8 * 65];
    const int bid = blockIdx.x;
    const int n   = bid & 7;
    const int rem = bid >> 3;
    const int hg  = rem >> 12;
    const int i   = rem & 4095;
    const int lane = threadIdx.x & 63;
    const int w    = threadIdx.x >> 6;
    const int h    = hg * 4 + w;
    const int g    = lane & 7;
    const int grp  = lane >> 3;
    const size_t rowbase = ((size_t)(n * L + i)) * CH + h * DD;

    fp16x2 qq[4];
    {
        const half8 qu = *(const half8*)(qb + rowbase + g * 8);
        const _Float16 sc = (_Float16)(0.125f * 1.44269504088896f);
        h2 qh[4];
#pragma unroll
        for (int e = 0; e < 4; e++) {
            qh[e][0] = qu[2 * e] * sc;
            qh[e][1] = qu[2 * e + 1] * sc;
        }
        __builtin_memcpy(qq, qh, 16);
    }
    const int start = rowptr[i], end = rowptr[i + 1];
    const char* kb_u = (const char*)(kb + (size_t)n * L * CH + h * DD);
    const char* vb_u = (const char*)(vb + (size_t)n * L * CH + h * DD);
    const int goff = g << 4;

    h2 oA[4] = {}, oB[4] = {};
    float lsA = 0.f, lsB = 0.f;

    const int nIt = (end - start + 15) >> 4;
    int idx = start + grp;
    const int last = end - 1;
    half8 kA{}, vA{}, kB{}, vB{};
    int jA1 = 0, jB1 = 0;
    if (nIt > 0) {
        const int jA0 = ecol[min(idx, last)];
        const int jB0 = ecol[min(idx + 8, last)];
        kA = *(const half8*)(kb_u + ((jA0 << 10) + goff));
        vA = *(const half8*)(vb_u + ((jA0 << 10) + goff));
        kB = *(const half8*)(kb_u + ((jB0 << 10) + goff));
        vB = *(const half8*)(vb_u + ((jB0 << 10) + goff));
        jA1 = ecol[min(idx + 16, last)];
        jB1 = ecol[min(idx + 24, last)];
    }

    for (int it = 0; it < nIt; ++it) {
        const half8 kAn = *(const half8*)(kb_u + ((jA1 << 10) + goff));
        const half8 vAn = *(const half8*)(vb_u + ((jA1 << 10) + goff));
        const half8 kBn = *(const half8*)(kb_u + ((jB1 << 10) + goff));
        const half8 vBn = *(const half8*)(vb_u + ((jB1 << 10) + goff));
        const int jA2 = ecol[min(idx + 32, last)];
        const int jB2 = ecol[min(idx + 40, last)];
        const bool vdA = idx < end;
        const bool vdB = idx + 8 < end;
        fp16x2 ka[4], kb2[4];
        __builtin_memcpy(ka, &kA, 16);
        __builtin_memcpy(kb2, &kB, 16);
        float sA = 0.f, sB = 0.f;
#if __has_builtin(__builtin_amdgcn_fdot2)
#pragma unroll
        for (int e = 0; e < 4; e++) {
            sA = __builtin_amdgcn_fdot2(ka[e],  qq[e], sA, false);
            sB = __builtin_amdgcn_fdot2(kb2[e], qq[e], sB, false);
        }
#else
#pragma unroll
        for (int e = 0; e < 4; e++) {
            sA = fmaf((float)ka[e][0],  (float)qq[e][0], sA);
            sA = fmaf((float)ka[e][1],  (float)qq[e][1], sA);
            sB = fmaf((float)kb2[e][0], (float)qq[e][0], sB);
            sB = fmaf((float)kb2[e][1], (float)qq[e][1], sB);
        }
#endif
        sA = dppadd<0xB1>(sA);  sB = dppadd<0xB1>(sB);
        sA = dppadd<0x4E>(sA);  sB = dppadd<0x4E>(sB);
        sA = dppadd<0x141>(sA); sB = dppadd<0x141>(sB);
        float peA = exp2f(sA); peA = vdA ? peA : 0.f;
        float peB = exp2f(sB); peB = vdB ? peB : 0.f;
        const _Float16 phA = (_Float16)peA, phB = (_Float16)peB;
        const h2 pa2 = {phA, phA}, pb2 = {phB, phB};
        h2 va2[4], vb2[4];
        __builtin_memcpy(va2, &vA, 16);
        __builtin_memcpy(vb2, &vB, 16);
#pragma unroll
        for (int e = 0; e < 4; e++) {
            oA[e] += pa2 * va2[e];
            oB[e] += pb2 * vb2[e];
        }
        lsA += peA; lsB += peB;
        kA = kAn; vA = vAn; kB = kBn; vB = vBn;
        jA1 = jA2; jB1 = jB2; idx += 16;
    }

    float lsum = lsA + lsB;
    lsum += __shfl_xor(lsum, 8);
    lsum += __shfl_xor(lsum, 16);
    lsum += __shfl_xor(lsum, 32);

    float o[8];
#pragma unroll
    for (int e = 0; e < 4; e++) {
        o[2 * e]     = (float)oA[e][0] + (float)oB[e][0];
        o[2 * e + 1] = (float)oA[e][1] + (float)oB[e][1];
    }
    float* p = part + w * (8 * 65);
    float* pw = p + grp * 65 + g * 8;
    *(f32x4*)(pw)     = *(f32x4*)&o[0];
    *(f32x4*)(pw + 4) = *(f32x4*)&o[4];
    __builtin_amdgcn_s_waitcnt(0);
    float osum = 0.f;
#pragma unroll
    for (int gg = 0; gg < 8; gg++)
        osum += p[gg * 65 + lane];

    const float inv = (end > start) ? 1.f / lsum : 0.f;
    agg[rowbase + lane] = (_Float16)(osum * inv);
}

extern "C" void kernel_launch(void* const* d_in, const int* in_sizes, int n_in,
                              void* d_out, int out_size, void* d_ws, size_t ws_size,
                              hipStream_t stream)
{
    (void)in_sizes; (void)n_in; (void)out_size;
    const float* queries = (const float*)d_in[0];
    const float* keys    = (const float*)d_in[1];
    const float* values  = (const float*)d_in[2];
    const int*   adj     = (const int*)d_in[3];
    const float* Wq  = (const float*)d_in[4];
    const float* bq  = (const float*)d_in[5];
    const float* Wk  = (const float*)d_in[6];
    const float* bk  = (const float*)d_in[7];
    const float* Wv  = (const float*)d_in[8];
    const float* bv  = (const float*)d_in[9];
    const float* Wfc = (const float*)d_in[10];
    const float* bfc = (const float*)d_in[11];

    _Float16* qb = (_Float16*)d_out;                   // 33.5 MB (d_out dead until final)
    _Float16* kb = qb + (size_t)M_ROWS * CH;           // 33.5 MB
    uint8_t* w = (uint8_t*)d_ws;
    _Float16* vb   = (_Float16*)(w);                              // 33.5 MB
    _Float16* stgA = (_Float16*)(w + 33554432);                   // 33.5 MB (agg aliases)
    _Float16* agg  = stgA;
    _Float16* wf   = (_Float16*)(w + 67108864);                   // 2 MB (4 weights)
    int* cnt    = (int*)(w + 69206016);
    int* fill   = (int*)(w + 69206016 + 16384);
    int* rowptr = (int*)(w + 69206016 + 32768);
    int* ecol   = (int*)(w + 69206016 + 65536);                   // 512 KB -> ends 69,795,840
    _Float16* stgB = (_Float16*)(w + 69795840);                   // 33.5 MB (overlap path only)
    constexpr size_t WS_NEED = 69795840ull + 33554432ull;         // 103,350,272

    if (ws_size >= WS_NEED) {
        // ---- overlap path: 6 dispatches ----
        fusedD0<<<dim3(8720), 256, 0, stream>>>(queries, stgA, Wq, Wk, Wv, Wfc,
                                                wf, cnt, fill);
        fusedD1<<<dim3(9728), 256, 0, stream>>>(stgA, wf + 0 * WELEM, bq, qb,
                                                keys, stgB, adj, cnt);
        fusedD2<<<dim3(9217), 256, 0, stream>>>(stgB, wf + 1 * WELEM, bk, kb,
                                                values, stgA, cnt, rowptr);
        fusedD3<<<dim3(1536), 256, 0, stream>>>(stgA, wf + 2 * WELEM, bv, vb,
                                                adj, rowptr, fill, ecol);
        attn_k<<<dim3(2 * NB * L), 256, 0, stream>>>(qb, kb, vb, rowptr, ecol, agg);
        gemm_f16<true><<<dim3(1024), 256, 0, stream>>>(agg, wf + 3 * WELEM, bfc,
                                                       (float*)d_out);
    } else {
        // ---- serial fallback (round-11 proven order, single staging) ----
        _Float16* stg = stgA;
        cvtw_k<<<dim3(512), 256, 0, stream>>>(Wq, Wk, Wv, Wfc, wf);
        zero_k<<<dim3(16), 256, 0, stream>>>(cnt, fill);
        count_k<<<dim3(512), 256, 0, stream>>>(adj, cnt);
        scan_k<<<dim3(1), 256, 0, stream>>>(cnt, rowptr);
        scatter_k<<<dim3(512), 256, 0, stream>>>(adj, rowptr, fill, ecol);
        cvt8_k<<<dim3(8192), 256, 0, stream>>>(queries, stg);
        gemm_f16<false><<<dim3(1024), 256, 0, stream>>>(stg, wf + 0 * WELEM, bq, qb);
        cvt8_k<<<dim3(8192), 256, 0, stream>>>(keys, stg);
        gemm_f16<false><<<dim3(1024), 256, 0, stream>>>(stg, wf + 1 * WELEM, bk, kb);
        cvt8_k<<<dim3(8192), 256, 0, stream>>>(values, stg);
        gemm_f16<false><<<dim3(1024), 256, 0, stream>>>(stg, wf + 2 * WELEM, bv, vb);
        attn_k<<<dim3(2 * NB * L), 256, 0, stream>>>(qb, kb, vb, rowptr, ecol, agg);
        gemm_f16<true><<<dim3(1024), 256, 0, stream>>>(agg, wf + 3 * WELEM, bfc,
                                                       (float*)d_out);
    }
}